// Round 10
// baseline (768.308 us; speedup 1.0000x reference)
//
#include <hip/hip_runtime.h>

#define NDEV 8192
#define NAP  4
#define NSAMP 32768
#define EDD 262144
#define EDA 32768
#define EAD 32768
#define CHUNK 8192
#define KC 128
#define ASTR2 132

typedef float vf2 __attribute__((ext_vector_type(2)));
static __device__ __forceinline__ vf2 pk_fma(vf2 a, vf2 b, vf2 c) {
    return __builtin_elementwise_fma(a, b, c);
}

// ---------------------------------------------------------------------------
// Repack conv2 weights to vf2 pairs (round-5 proven layout).
// ---------------------------------------------------------------------------
__global__ void repack_kernel(const float* __restrict__ w2, float* __restrict__ wpk)
{
    int i = blockIdx.x * 256 + threadIdx.x;
    if (i < 4608) {
        int h = i & 1, p = i >> 1;
        int k = p % 9, r = p / 9;
        int q = r & 15, ic = r >> 4;
        wpk[i] = w2[(2 * q + h) * 144 + ic * 9 + k];
    }
}

// ---------------------------------------------------------------------------
// conv1+conv2 (round-5 proven kernel, unchanged).
// ---------------------------------------------------------------------------
__global__ __launch_bounds__(256) void conv_kernel(
    const float* __restrict__ csi,
    float* __restrict__ c2,
    const float* __restrict__ w1, const float* __restrict__ b1,
    const float* __restrict__ wpk, const float* __restrict__ b2)
{
    __shared__ float sw1[288];
    __shared__ float sb1[16];
    __shared__ float sb2[32];
    __shared__ float inpad[4][2][10][10];
    __shared__ float c1pad[7712];
    const int tid = threadIdx.x;

    for (int i = tid; i < 288; i += 256) sw1[i] = w1[i];
    if (tid < 16) sb1[tid] = b1[tid];
    if (tid < 32) sb2[tid] = b2[tid];
    float* ip = &inpad[0][0][0][0];
    for (int i = tid; i < 800; i += 256) ip[i] = 0.f;
    for (int i = tid; i < 7712; i += 256) c1pad[i] = 0.f;
    __syncthreads();

    const long s0 = (long)blockIdx.x * 4;
    for (int i = tid; i < 512; i += 256) {
        int si = i >> 7, r = i & 127;
        int f = r >> 4, t = (r >> 1) & 7, c = r & 1;
        inpad[si][c][f + 1][t + 1] = csi[s0 * 128 + i];
    }
    __syncthreads();

    for (int j = 0; j < 16; ++j) {
        int idx = tid + j * 256;
        int t = idx & 7, f = (idx >> 3) & 7, oc = (idx >> 6) & 15, si = idx >> 10;
        float acc = sb1[oc];
        #pragma unroll
        for (int ic = 0; ic < 2; ++ic)
            #pragma unroll
            for (int df = 0; df < 3; ++df)
                #pragma unroll
                for (int dt = 0; dt < 3; ++dt)
                    acc += inpad[si][ic][f + df][t + dt] * sw1[((oc * 2 + ic) * 3 + df) * 3 + dt];
        c1pad[si * 1928 + oc * 120 + (f + 1) * 12 + (t + 1)] = fmaxf(acc, 0.f);
    }
    __syncthreads();

    const int wv = __builtin_amdgcn_readfirstlane(tid >> 6);
    const int lane = tid & 63;
    const int pos = lane & 31;
    const int si = pos >> 3, fr = pos & 7;
    const int th = lane >> 5, tb = th * 4;
    const vf2* __restrict__ wv2 = (const vf2*)wpk;

    vf2 accp[4][4];
    #pragma unroll
    for (int op = 0; op < 4; ++op) {
        int q = wv * 4 + op;
        vf2 b = {sb2[2 * q], sb2[2 * q + 1]};
        #pragma unroll
        for (int t = 0; t < 4; ++t) accp[op][t] = b;
    }

    for (int ic = 0; ic < 16; ++ic) {
        float rr[3][6];
        const int base = si * 1928 + ic * 120 + fr * 12 + tb;
        #pragma unroll
        for (int r = 0; r < 3; ++r) {
            float4 a = *(const float4*)&c1pad[base + r * 12];
            float2 b = *(const float2*)&c1pad[base + r * 12 + 4];
            rr[r][0] = a.x; rr[r][1] = a.y; rr[r][2] = a.z; rr[r][3] = a.w;
            rr[r][4] = b.x; rr[r][5] = b.y;
        }
        const vf2* wp = wv2 + (size_t)(ic * 16 + wv * 4) * 9;
        vf2 w[36];
        #pragma unroll
        for (int u = 0; u < 36; ++u) w[u] = wp[u];
        #pragma unroll
        for (int op = 0; op < 4; ++op) {
            #pragma unroll
            for (int df = 0; df < 3; ++df)
                #pragma unroll
                for (int dt = 0; dt < 3; ++dt) {
                    vf2 wq = w[op * 9 + df * 3 + dt];
                    #pragma unroll
                    for (int t = 0; t < 4; ++t) {
                        vf2 sv = {rr[df][t + dt], rr[df][t + dt]};
                        accp[op][t] = pk_fma(sv, wq, accp[op][t]);
                    }
                }
        }
    }
    #pragma unroll
    for (int op = 0; op < 4; ++op) {
        int q = wv * 4 + op;
        float4 lo, hi;
        lo.x = fmaxf(accp[op][0].x, 0.f); lo.y = fmaxf(accp[op][1].x, 0.f);
        lo.z = fmaxf(accp[op][2].x, 0.f); lo.w = fmaxf(accp[op][3].x, 0.f);
        hi.x = fmaxf(accp[op][0].y, 0.f); hi.y = fmaxf(accp[op][1].y, 0.f);
        hi.z = fmaxf(accp[op][2].y, 0.f); hi.w = fmaxf(accp[op][3].y, 0.f);
        *(float4*)&c2[(s0 + si) * 2048 + (long)(2 * q) * 64 + fr * 8 + tb] = lo;
        *(float4*)&c2[(s0 + si) * 2048 + (long)(2 * q + 1) * 64 + fr * 8 + tb] = hi;
    }
}

// ---------------------------------------------------------------------------
// fcs: [CHUNK,2048]@[2048,64] -> partials. lane = m (64 rows), wave = 16-o
// slab (W wave-uniform -> SMEM pipe, free VALU operands), A via LDS b128 at
// the 1KB/wave floor. K-split 4 across blocks; grid (CHUNK/64)*4 = 512.
// ---------------------------------------------------------------------------
__global__ __launch_bounds__(256) void fcs_kernel(
    const float* __restrict__ A,    // [CHUNK][2048]
    const float* __restrict__ W,    // [2048][64]
    float* __restrict__ partials)   // [4][CHUNK][64]
{
    __shared__ __align__(16) float As[64 * ASTR2];   // 33.8 KB
    const int tid = threadIdx.x;
    const int oslab = __builtin_amdgcn_readfirstlane(tid >> 6);  // 0..3
    const int lane = tid & 63;                                   // m row
    const int mt = blockIdx.x >> 2;
    const int ks = blockIdx.x & 3;
    const long m0 = (long)mt * 64;
    const int kbase0 = ks * 512;

    vf2 acc[8];
    #pragma unroll
    for (int i = 0; i < 8; ++i) acc[i] = (vf2){0.f, 0.f};

    for (int kc = 0; kc < 4; ++kc) {
        const int kb = kbase0 + kc * 128;
        __syncthreads();
        #pragma unroll
        for (int i = 0; i < 8; ++i) {
            int idx = tid + i * 256;
            int m = idx >> 5, kq = idx & 31;
            *(float4*)&As[m * ASTR2 + kq * 4] =
                *(const float4*)&A[(m0 + m) * 2048 + kb + kq * 4];
        }
        __syncthreads();
        const float* wbase = W + (size_t)kb * 64 + oslab * 16;
        #pragma unroll 4
        for (int kk = 0; kk < 32; ++kk) {
            float4 a4 = *(const float4*)&As[lane * ASTR2 + kk * 4];
            const float* wr = wbase + (size_t)kk * 256;  // 4 k-rows of 64
            float am[4] = {a4.x, a4.y, a4.z, a4.w};
            #pragma unroll
            for (int j = 0; j < 4; ++j) {
                const vf2* wvp = (const vf2*)(wr + j * 64);
                vf2 av = {am[j], am[j]};
                #pragma unroll
                for (int u = 0; u < 8; ++u)
                    acc[u] = pk_fma(av, wvp[u], acc[u]);
            }
        }
    }
    float* pp = partials + ((size_t)ks * CHUNK + m0 + lane) * 64 + oslab * 16;
    #pragma unroll
    for (int q = 0; q < 4; ++q) {
        float4 o;
        o.x = acc[2 * q].x;     o.y = acc[2 * q].y;
        o.z = acc[2 * q + 1].x; o.w = acc[2 * q + 1].y;
        *(float4*)&pp[q * 4] = o;
    }
}

// Reduce 4 k-slice partials + bias + relu -> emb [CHUNK][64].
__global__ __launch_bounds__(256) void fcred_kernel(
    const float* __restrict__ partials, const float* __restrict__ bias,
    float* __restrict__ emb)
{
    const int idx = blockIdx.x * 256 + threadIdx.x;  // float4 index
    const float4* P = (const float4*)partials;
    float4 p0 = P[idx];
    float4 p1 = P[idx + CHUNK * 16];
    float4 p2 = P[idx + CHUNK * 32];
    float4 p3 = P[idx + CHUNK * 48];
    const float4 b = ((const float4*)bias)[idx & 15];
    float4 o;
    o.x = fmaxf(p0.x + p1.x + p2.x + p3.x + b.x, 0.f);
    o.y = fmaxf(p0.y + p1.y + p2.y + p3.y + b.y, 0.f);
    o.z = fmaxf(p0.z + p1.z + p2.z + p3.z + b.z, 0.f);
    o.w = fmaxf(p0.w + p1.w + p2.w + p3.w + b.w, 0.f);
    ((float4*)emb)[idx] = o;
}

// ---------------------------------------------------------------------------
// fc16 (round-9 proven form) for the K=256 device-csi GEMM.
// ---------------------------------------------------------------------------
__global__ __launch_bounds__(256) void fc16_kernel(
    const float* __restrict__ A, const float* __restrict__ W,
    const float* __restrict__ bias, float* __restrict__ out, int K)
{
    __shared__ __align__(16) float smem[16 * ASTR2 + KC * 64];
    float* As = smem;
    float* Ws = smem + 16 * ASTR2;
    const int tid = threadIdx.x;
    const long m0g = (long)blockIdx.x * 16;
    const int ks = tid >> 6;
    const int lane = tid & 63;
    const int m0 = (lane >> 4) * 4;
    const int o0 = (lane & 15) * 4;

    vf2 accp[4][2];
    #pragma unroll
    for (int i = 0; i < 4; ++i) { accp[i][0] = (vf2){0.f, 0.f}; accp[i][1] = (vf2){0.f, 0.f}; }

    for (int kc = 0; kc < K; kc += KC) {
        __syncthreads();
        #pragma unroll
        for (int i = 0; i < 2; ++i) {
            int idx = tid + i * 256;
            int m = idx >> 5, kq = idx & 31;
            float4 v = *(const float4*)&A[(m0g + m) * K + kc + kq * 4];
            *(float4*)&As[m * ASTR2 + kq * 4] = v;
        }
        #pragma unroll
        for (int i = 0; i < 8; ++i) {
            int idx = tid + i * 256;
            int k = idx >> 4, oq = idx & 15;
            *(float4*)&Ws[k * 64 + oq * 4] = *(const float4*)&W[(long)(kc + k) * 64 + oq * 4];
        }
        __syncthreads();
        const int kb = ks * 32;
        #pragma unroll 4
        for (int kk4 = 0; kk4 < 8; ++kk4) {
            const int k0 = kb + kk4 * 4;
            float4 a[4], w[4];
            #pragma unroll
            for (int i = 0; i < 4; ++i) a[i] = *(const float4*)&As[(m0 + i) * ASTR2 + k0];
            #pragma unroll
            for (int j = 0; j < 4; ++j) w[j] = *(const float4*)&Ws[(k0 + j) * 64 + o0];
            #pragma unroll
            for (int j = 0; j < 4; ++j) {
                vf2 w01 = {w[j].x, w[j].y}, w23 = {w[j].z, w[j].w};
                float av[4] = {j == 0 ? a[0].x : (j == 1 ? a[0].y : (j == 2 ? a[0].z : a[0].w)),
                               j == 0 ? a[1].x : (j == 1 ? a[1].y : (j == 2 ? a[1].z : a[1].w)),
                               j == 0 ? a[2].x : (j == 1 ? a[2].y : (j == 2 ? a[2].z : a[2].w)),
                               j == 0 ? a[3].x : (j == 1 ? a[3].y : (j == 2 ? a[3].z : a[3].w))};
                #pragma unroll
                for (int i = 0; i < 4; ++i) {
                    vf2 a2 = {av[i], av[i]};
                    accp[i][0] = pk_fma(a2, w01, accp[i][0]);
                    accp[i][1] = pk_fma(a2, w23, accp[i][1]);
                }
            }
        }
    }
    __syncthreads();
    float* red = smem;
    #pragma unroll
    for (int i = 0; i < 4; ++i) {
        red[(ks * 16 + m0 + i) * 64 + o0 + 0] = accp[i][0].x;
        red[(ks * 16 + m0 + i) * 64 + o0 + 1] = accp[i][0].y;
        red[(ks * 16 + m0 + i) * 64 + o0 + 2] = accp[i][1].x;
        red[(ks * 16 + m0 + i) * 64 + o0 + 3] = accp[i][1].y;
    }
    __syncthreads();
    {
        int m = tid >> 4, oq = tid & 15;
        float4 r0 = *(float4*)&red[(0 * 16 + m) * 64 + oq * 4];
        float4 r1 = *(float4*)&red[(1 * 16 + m) * 64 + oq * 4];
        float4 r2 = *(float4*)&red[(2 * 16 + m) * 64 + oq * 4];
        float4 r3 = *(float4*)&red[(3 * 16 + m) * 64 + oq * 4];
        const float4 b4 = *(const float4*)&bias[oq * 4];
        float4 o4;
        o4.x = fmaxf(r0.x + r1.x + r2.x + r3.x + b4.x, 0.f);
        o4.y = fmaxf(r0.y + r1.y + r2.y + r3.y + b4.y, 0.f);
        o4.z = fmaxf(r0.z + r1.z + r2.z + r3.z + b4.z, 0.f);
        o4.w = fmaxf(r0.w + r1.w + r2.w + r3.w + b4.w, 0.f);
        *(float4*)&out[(m0g + m) * 64 + oq * 4] = o4;
    }
}

// ---------------------------------------------------------------------------
__global__ __launch_bounds__(256) void merge_kernel(
    const float* __restrict__ dpos, const int* __restrict__ pkts,
    const float* __restrict__ csif,
    const float* __restrict__ Wp, const float* __restrict__ bp,
    const float* __restrict__ Wm, const float* __restrict__ bm,
    const int* __restrict__ degout,
    float* __restrict__ hdev, float* __restrict__ xn)
{
    __shared__ float sWm[80][64];
    __shared__ float spos[4][16];
    __shared__ float scf[4][64];
    const int tid = threadIdx.x;
    for (int i = tid; i < 5120; i += 256) sWm[i >> 6][i & 63] = Wm[i];
    const int n0 = blockIdx.x * 4;
    (&scf[0][0])[tid] = csif[(long)n0 * 64 + tid];
    if (tid < 64) {
        int dl = tid >> 4, o = tid & 15;
        int d = n0 + dl;
        float px = dpos[d * 2], py = dpos[d * 2 + 1], pk = (float)pkts[d];
        float v = bp[o] + px * Wp[o] + py * Wp[16 + o] + pk * Wp[32 + o];
        spos[dl][o] = fmaxf(v, 0.f);
    }
    __syncthreads();
    const int o = tid & 63, dl = tid >> 6;
    float h = bm[o];
    #pragma unroll
    for (int j = 0; j < 16; ++j) h += spos[dl][j] * sWm[j][o];
    #pragma unroll 8
    for (int j = 0; j < 64; ++j) h += scf[dl][j] * sWm[16 + j][o];
    h = fmaxf(h, 0.f);
    const long idx = (long)(n0 + dl) * 64 + o;
    hdev[idx] = h;
    xn[idx] = h * rsqrtf(fmaxf((float)degout[n0 + dl], 1.f));
}

__global__ void ap_enc_kernel(const float* __restrict__ appos,
                              const float* __restrict__ W, const float* __restrict__ b,
                              const int* __restrict__ degout,
                              float* __restrict__ hap, float* __restrict__ xnap)
{
    int tid = threadIdx.x;
    int a = tid >> 6, o = tid & 63;
    float v = fmaxf(b[o] + appos[a * 2] * W[o] + appos[a * 2 + 1] * W[64 + o], 0.f);
    hap[tid] = v;
    xnap[tid] = v * rsqrtf(fmaxf((float)degout[a], 1.f));
}

// ---------------------------------------------------------------------------
__global__ __launch_bounds__(256) void degrees_kernel(
    const int* __restrict__ dd_src, const int* __restrict__ dd_dst,
    const int* __restrict__ da_src, const int* __restrict__ da_dst,
    const int* __restrict__ ad_src, const int* __restrict__ ad_dst,
    int* deg_dd_out, int* deg_dd_in, int* deg_da_out, int* deg_ad_in, int* deg_small)
{
    __shared__ int s4[16];
    const int tid = threadIdx.x;
    if (tid < 16) s4[tid] = 0;
    __syncthreads();
    const int gid = blockIdx.x * 256 + tid;
    atomicAdd(&deg_dd_out[dd_src[gid]], 1);
    atomicAdd(&deg_dd_in[dd_dst[gid]], 1);
    if (gid < EDA) {
        atomicAdd(&deg_da_out[da_src[gid]], 1);
        atomicAdd(&s4[da_dst[gid]], 1);
        atomicAdd(&s4[8 + ad_src[gid]], 1);
        atomicAdd(&deg_ad_in[ad_dst[gid]], 1);
    }
    __syncthreads();
    if (tid < 16 && s4[tid] != 0) atomicAdd(&deg_small[tid], s4[tid]);
}

__global__ __launch_bounds__(1024) void scan_kernel(
    const int* __restrict__ degA, int* rsA, int* curA,
    const int* __restrict__ degB, int* rsB, int* curB)
{
    const int* deg = blockIdx.x ? degB : degA;
    int* rs = blockIdx.x ? rsB : rsA;
    int* cur = blockIdx.x ? curB : curA;
    __shared__ int sd[1024];
    const int tid = threadIdx.x;
    const int base = tid * 8;
    int v[8]; int s = 0;
    #pragma unroll
    for (int j = 0; j < 8; ++j) { v[j] = deg[base + j]; s += v[j]; }
    sd[tid] = s;
    __syncthreads();
    for (int off = 1; off < 1024; off <<= 1) {
        int t = (tid >= off) ? sd[tid - off] : 0;
        __syncthreads();
        sd[tid] += t;
        __syncthreads();
    }
    int ex = sd[tid] - s;
    #pragma unroll
    for (int j = 0; j < 8; ++j) { rs[base + j] = ex; cur[base + j] = ex; ex += v[j]; }
}

__global__ __launch_bounds__(256) void reorder_kernel(
    const int* __restrict__ src, const int* __restrict__ dst,
    int* __restrict__ cursor, int* __restrict__ ssrc, int nE)
{
    int e = blockIdx.x * 256 + threadIdx.x;
    if (e < nE) {
        int pos = atomicAdd(&cursor[dst[e]], 1);
        ssrc[pos] = src[e];
    }
}

// ---------------------------------------------------------------------------
__global__ __launch_bounds__(256) void gather_kernel(
    const int* __restrict__ row_start, const int* __restrict__ deg_in,
    const int* __restrict__ ssrc, const float* __restrict__ xn,
    float* __restrict__ agg)
{
    const int tid = threadIdx.x;
    const int w = __builtin_amdgcn_readfirstlane(tid >> 6);
    const int f = tid & 63;
    const int d = blockIdx.x * 4 + w;
    const int start = row_start[d], len = deg_in[d];
    float acc = 0.f;
    int j = 0;
    for (; j + 4 <= len; j += 4) {
        int s0 = ssrc[start + j], s1 = ssrc[start + j + 1];
        int s2 = ssrc[start + j + 2], s3 = ssrc[start + j + 3];
        float v0 = xn[(long)s0 * 64 + f], v1 = xn[(long)s1 * 64 + f];
        float v2 = xn[(long)s2 * 64 + f], v3 = xn[(long)s3 * 64 + f];
        acc += (v0 + v1) + (v2 + v3);
    }
    for (; j < len; ++j) acc += xn[(long)ssrc[start + j] * 64 + f];
    agg[(long)d * 64 + f] = acc * rsqrtf(fmaxf((float)len, 1.f));
}

__global__ __launch_bounds__(256) void da_reduce_kernel(
    const int* __restrict__ src, const int* __restrict__ dst,
    const float* __restrict__ x, const int* __restrict__ deg_out,
    float* __restrict__ agg)
{
    __shared__ float sacc[4][64];
    const int tid = threadIdx.x;
    (&sacc[0][0])[tid] = 0.f;
    __syncthreads();
    const int f = tid & 63;
    const int base = blockIdx.x * 128;
    for (int e = base + (tid >> 6); e < base + 128; e += 4) {
        int s = src[e], d = dst[e];
        float sc = rsqrtf(fmaxf((float)deg_out[s], 1.f));
        atomicAdd(&sacc[d][f], x[(long)s * 64 + f] * sc);
    }
    __syncthreads();
    float v = (&sacc[0][0])[tid];
    if (v != 0.f) atomicAdd(&agg[tid], v);
}

// ---------------------------------------------------------------------------
__global__ __launch_bounds__(256) void combine_hd_kernel(
    const float* __restrict__ agg1, const float* __restrict__ W1, const float* __restrict__ b1,
    const float* __restrict__ agg2, const float* __restrict__ W2, const float* __restrict__ b2,
    const int* __restrict__ degout, float* __restrict__ out, float* __restrict__ xnout)
{
    __shared__ float sW1[64][64];
    __shared__ float sW2[64][64];
    __shared__ float sa1[4][64];
    __shared__ float sa2[4][64];
    const int tid = threadIdx.x;
    for (int i = tid; i < 4096; i += 256) { sW1[i >> 6][i & 63] = W1[i]; sW2[i >> 6][i & 63] = W2[i]; }
    const int n0 = blockIdx.x * 4;
    (&sa1[0][0])[tid] = agg1[(long)n0 * 64 + tid];
    (&sa2[0][0])[tid] = agg2[(long)n0 * 64 + tid];
    __syncthreads();
    const int o = tid & 63, dl = tid >> 6;
    float acc1 = 0.f, acc2 = 0.f;
    #pragma unroll 8
    for (int k = 0; k < 64; ++k) {
        acc1 += sa1[dl][k] * sW1[k][o];
        acc2 += sa2[dl][k] * sW2[k][o];
    }
    float h = fmaxf(acc1 + acc2 + b1[o] + b2[o], 0.f);
    const long idx = (long)(n0 + dl) * 64 + o;
    out[idx] = h;
    if (xnout) xnout[idx] = h * rsqrtf(fmaxf((float)degout[n0 + dl], 1.f));
}

__global__ void combine_ha_kernel(const float* __restrict__ agg, const int* __restrict__ degin,
                                  const float* __restrict__ W, const float* __restrict__ b,
                                  const int* __restrict__ degout,
                                  float* __restrict__ out, float* __restrict__ xnout)
{
    const int tid = threadIdx.x;
    const int o = tid & 63, a = tid >> 6;
    float acc = 0.f;
    for (int k = 0; k < 64; ++k) acc += agg[a * 64 + k] * W[k * 64 + o];
    float r = rsqrtf(fmaxf((float)degin[a], 1.f));
    float h = fmaxf(acc * r + b[o], 0.f);
    out[tid] = h;
    xnout[tid] = h * rsqrtf(fmaxf((float)degout[a], 1.f));
}

// ---------------------------------------------------------------------------
__global__ __launch_bounds__(256) void head_kernel(
    const float* __restrict__ hd2,
    const float* __restrict__ W1, const float* __restrict__ b1,
    const float* __restrict__ W2, const float* __restrict__ b2,
    float* __restrict__ logits_out)
{
    __shared__ float sW1[64][64];
    __shared__ float sW2[64][32];
    __shared__ float sh[4][64];
    __shared__ float st[4][64];
    const int tid = threadIdx.x;
    for (int i = tid; i < 4096; i += 256) sW1[i >> 6][i & 63] = W1[i];
    for (int i = tid; i < 2048; i += 256) sW2[i >> 5][i & 31] = W2[i];
    const int n0 = blockIdx.x * 4;
    (&sh[0][0])[tid] = hd2[(long)n0 * 64 + tid];
    __syncthreads();
    const int o = tid & 63, dl = tid >> 6;
    float acc = b1[o];
    #pragma unroll 8
    for (int k = 0; k < 64; ++k) acc += sh[dl][k] * sW1[k][o];
    st[dl][o] = fmaxf(acc, 0.f);
    __syncthreads();
    if (tid < 128) {
        int j = tid & 31, d2 = tid >> 5;
        float a2 = b2[j];
        #pragma unroll 8
        for (int k = 0; k < 64; ++k) a2 += st[d2][k] * sW2[k][j];
        logits_out[(long)(n0 + d2) * 32 + j] = a2;
    }
}

// ---------------------------------------------------------------------------
__global__ __launch_bounds__(1024) void softmax_stats_kernel(
    const float* __restrict__ logits,
    float* __restrict__ smax, int* __restrict__ sargm, float* __restrict__ ssum)
{
    __shared__ float smx[1024];
    __shared__ int sid[1024];
    __shared__ float ssm[1024];
    const int j = blockIdx.x;
    const int tid = threadIdx.x;
    float best = -__builtin_inff(); int bid = 0x7fffffff;
    for (int n = tid; n < NDEV; n += 1024) {
        float v = logits[n * 32 + j];
        if (v > best) { best = v; bid = n; }
    }
    smx[tid] = best; sid[tid] = bid;
    __syncthreads();
    for (int s = 512; s > 0; s >>= 1) {
        if (tid < s) {
            float v2 = smx[tid + s]; int i2 = sid[tid + s];
            if (v2 > smx[tid] || (v2 == smx[tid] && i2 < sid[tid])) { smx[tid] = v2; sid[tid] = i2; }
        }
        __syncthreads();
    }
    const float mx = smx[0];
    float part = 0.f;
    for (int n = tid; n < NDEV; n += 1024) part += expf(logits[n * 32 + j] - mx);
    ssm[tid] = part;
    __syncthreads();
    for (int s = 512; s > 0; s >>= 1) {
        if (tid < s) ssm[tid] += ssm[tid + s];
        __syncthreads();
    }
    if (tid == 0) { smax[j] = mx; sargm[j] = sid[0]; ssum[j] = ssm[0]; }
}

__global__ __launch_bounds__(256) void final_kernel(
    const float* __restrict__ logits, const float* __restrict__ smax,
    const int* __restrict__ sargm, const float* __restrict__ ssum,
    float* __restrict__ hard, float* __restrict__ soft)
{
    const int gid = blockIdx.x * 256 + threadIdx.x;
    const int n = gid >> 3, t = gid & 7;
    float s = 0.f; int h = 0;
    #pragma unroll
    for (int a = 0; a < 4; ++a) {
        int j = t * 4 + a;
        s += expf(logits[n * 32 + j] - smax[j]) / ssum[j];
        h |= (sargm[j] == n) ? 1 : 0;
    }
    hard[gid] = (float)h;
    soft[gid] = s;
}

// ---------------------------------------------------------------------------
extern "C" void kernel_launch(void* const* d_in, const int* in_sizes, int n_in,
                              void* d_out, int out_size, void* d_ws, size_t ws_size,
                              hipStream_t stream)
{
    const float* device_pos = (const float*)d_in[0];
    const float* ap_pos     = (const float*)d_in[1];
    const float* csi        = (const float*)d_in[2];
    const int*   node_pk    = (const int*)d_in[3];
    const int* dd_src = (const int*)d_in[4];
    const int* dd_dst = (const int*)d_in[5];
    const int* da_src = (const int*)d_in[6];
    const int* da_dst = (const int*)d_in[7];
    const int* ad_src = (const int*)d_in[8];
    const int* ad_dst = (const int*)d_in[9];
    const float* w1  = (const float*)d_in[10]; const float* b1  = (const float*)d_in[11];
    const float* w2  = (const float*)d_in[12]; const float* b2  = (const float*)d_in[13];
    const float* fcW = (const float*)d_in[14]; const float* fcb = (const float*)d_in[15];
    const float* Wp  = (const float*)d_in[16]; const float* bp  = (const float*)d_in[17];
    const float* Wc  = (const float*)d_in[18]; const float* bc  = (const float*)d_in[19];
    const float* Wm  = (const float*)d_in[20]; const float* bm  = (const float*)d_in[21];
    const float* Wap = (const float*)d_in[22]; const float* bap = (const float*)d_in[23];
    const float* g1ddW = (const float*)d_in[24]; const float* g1ddb = (const float*)d_in[25];
    const float* g1daW = (const float*)d_in[26]; const float* g1dab = (const float*)d_in[27];
    const float* g1adW = (const float*)d_in[28]; const float* g1adb = (const float*)d_in[29];
    const float* g2ddW = (const float*)d_in[30]; const float* g2ddb = (const float*)d_in[31];
    const float* g2adW = (const float*)d_in[34]; const float* g2adb = (const float*)d_in[35];
    const float* a1W = (const float*)d_in[36]; const float* a1b = (const float*)d_in[37];
    const float* a2W = (const float*)d_in[38]; const float* a2b = (const float*)d_in[39];

    float* ws = (float*)d_ws;
    size_t o_c2    = 0;                               // 16,777,216
    size_t o_part  = o_c2 + (size_t)CHUNK * 2048;     // 4*CHUNK*64 = 2,097,152
    size_t o_emb   = o_part + (size_t)4 * CHUNK * 64;
    size_t o_csif  = o_emb + (size_t)NSAMP * 64;
    size_t o_hdev  = o_csif + (size_t)NDEV * 64;
    size_t o_hap   = o_hdev + (size_t)NDEV * 64;      // 256
    size_t o_hd1   = o_hap + 256;
    size_t o_ha1   = o_hd1 + (size_t)NDEV * 64;       // 256
    size_t o_hd2   = o_ha1 + 256;
    size_t o_aggdd = o_hd2 + (size_t)NDEV * 64;
    size_t o_aggad = o_aggdd + (size_t)NDEV * 64;
    size_t o_xn    = o_aggad + (size_t)NDEV * 64;
    size_t o_xnap  = o_xn + (size_t)NDEV * 64;        // 256
    size_t o_wpk   = o_xnap + 256;                    // 4608
    // zero region
    size_t o_zero  = o_wpk + 4608;
    size_t o_degddo = o_zero;
    size_t o_degddi = o_degddo + NDEV;
    size_t o_degdao = o_degddi + NDEV;
    size_t o_degadi = o_degdao + NDEV;
    size_t o_degsm  = o_degadi + NDEV;        // int[16]
    size_t o_aggda  = o_degsm + 16;           // float[256]
    size_t o_zend   = o_aggda + 256;
    // non-zeroed
    size_t o_rsdd  = o_zend;
    size_t o_curdd = o_rsdd + NDEV;
    size_t o_rsad  = o_curdd + NDEV;
    size_t o_curad = o_rsad + NDEV;
    size_t o_ssdd  = o_curad + NDEV;          // int[262144]
    size_t o_ssad  = o_ssdd + EDD;            // int[32768]
    size_t o_smax  = o_ssad + EAD;
    size_t o_ssum  = o_smax + 32;
    size_t o_sargm = o_ssum + 32;

    float* out = (float*)d_out;
    float* out_hard   = out;                 // [8192][8]
    float* out_logits = out + 65536;         // [8192][32]
    float* out_soft   = out + 65536 + 262144;

    hipMemsetAsync((void*)(ws + o_zero), 0, (o_zend - o_zero) * sizeof(float), stream);
    repack_kernel<<<18, 256, 0, stream>>>(w2, ws + o_wpk);

    // graph prep
    degrees_kernel<<<EDD / 256, 256, 0, stream>>>(dd_src, dd_dst, da_src, da_dst, ad_src, ad_dst,
                                                  (int*)(ws + o_degddo), (int*)(ws + o_degddi),
                                                  (int*)(ws + o_degdao), (int*)(ws + o_degadi),
                                                  (int*)(ws + o_degsm));
    scan_kernel<<<2, 1024, 0, stream>>>((int*)(ws + o_degddi), (int*)(ws + o_rsdd), (int*)(ws + o_curdd),
                                        (int*)(ws + o_degadi), (int*)(ws + o_rsad), (int*)(ws + o_curad));
    reorder_kernel<<<EDD / 256, 256, 0, stream>>>(dd_src, dd_dst, (int*)(ws + o_curdd),
                                                  (int*)(ws + o_ssdd), EDD);
    reorder_kernel<<<EAD / 256, 256, 0, stream>>>(ad_src, ad_dst, (int*)(ws + o_curad),
                                                  (int*)(ws + o_ssad), EAD);

    // CSI encoder: conv -> fcs (K-split partials) -> reduce
    for (int c = 0; c < NSAMP / CHUNK; ++c) {
        const float* csi_c = csi + (size_t)c * CHUNK * 128;
        float* emb_c = ws + o_emb + (size_t)c * CHUNK * 64;
        conv_kernel<<<CHUNK / 4, 256, 0, stream>>>(csi_c, ws + o_c2, w1, b1, ws + o_wpk, b2);
        fcs_kernel<<<(CHUNK / 64) * 4, 256, 0, stream>>>(ws + o_c2, fcW, ws + o_part);
        fcred_kernel<<<CHUNK * 64 / 1024, 256, 0, stream>>>(ws + o_part, fcb, emb_c);
    }

    // device encoder
    fc16_kernel<<<NDEV / 16, 256, 0, stream>>>(ws + o_emb, Wc, bc, ws + o_csif, 256);
    merge_kernel<<<NDEV / 4, 256, 0, stream>>>(device_pos, node_pk, ws + o_csif,
                                               Wp, bp, Wm, bm, (int*)(ws + o_degddo),
                                               ws + o_hdev, ws + o_xn);
    ap_enc_kernel<<<1, 256, 0, stream>>>(ap_pos, Wap, bap, (int*)(ws + o_degsm) + 8,
                                         ws + o_hap, ws + o_xnap);

    // layer 1
    gather_kernel<<<NDEV / 4, 256, 0, stream>>>((int*)(ws + o_rsdd), (int*)(ws + o_degddi),
                                                (int*)(ws + o_ssdd), ws + o_xn, ws + o_aggdd);
    gather_kernel<<<NDEV / 4, 256, 0, stream>>>((int*)(ws + o_rsad), (int*)(ws + o_degadi),
                                                (int*)(ws + o_ssad), ws + o_xnap, ws + o_aggad);
    da_reduce_kernel<<<EDA / 128, 256, 0, stream>>>(da_src, da_dst, ws + o_hdev,
                                                    (int*)(ws + o_degdao), ws + o_aggda);
    combine_hd_kernel<<<NDEV / 4, 256, 0, stream>>>(ws + o_aggdd, g1ddW, g1ddb,
                                                    ws + o_aggad, g1adW, g1adb,
                                                    (int*)(ws + o_degddo), ws + o_hd1, ws + o_xn);
    combine_ha_kernel<<<1, 256, 0, stream>>>(ws + o_aggda, (int*)(ws + o_degsm),
                                             g1daW, g1dab, (int*)(ws + o_degsm) + 8,
                                             ws + o_ha1, ws + o_xnap);

    // layer 2
    gather_kernel<<<NDEV / 4, 256, 0, stream>>>((int*)(ws + o_rsdd), (int*)(ws + o_degddi),
                                                (int*)(ws + o_ssdd), ws + o_xn, ws + o_aggdd);
    gather_kernel<<<NDEV / 4, 256, 0, stream>>>((int*)(ws + o_rsad), (int*)(ws + o_degadi),
                                                (int*)(ws + o_ssad), ws + o_xnap, ws + o_aggad);
    combine_hd_kernel<<<NDEV / 4, 256, 0, stream>>>(ws + o_aggdd, g2ddW, g2ddb,
                                                    ws + o_aggad, g2adW, g2adb,
                                                    (int*)(ws + o_degddo), ws + o_hd2, nullptr);

    head_kernel<<<NDEV / 4, 256, 0, stream>>>(ws + o_hd2, a1W, a1b, a2W, a2b, out_logits);

    softmax_stats_kernel<<<32, 1024, 0, stream>>>(out_logits, ws + o_smax,
                                                  (int*)(ws + o_sargm), ws + o_ssum);
    final_kernel<<<65536 / 256, 256, 0, stream>>>(out_logits, ws + o_smax,
                                                  (int*)(ws + o_sargm), ws + o_ssum,
                                                  out_hard, out_soft);
    (void)in_sizes; (void)n_in; (void)out_size; (void)ws_size;
}

// Round 12
// 713.092 us; speedup vs baseline: 1.0774x; 1.0774x over previous
//
#include <hip/hip_runtime.h>

#define NDEV 8192
#define NAP  4
#define NSAMP 32768
#define EDD 262144
#define EDA 32768
#define EAD 32768
#define CHUNK 8192
#define KC 128
#define ASTR2 132

typedef float vf2 __attribute__((ext_vector_type(2)));
static __device__ __forceinline__ vf2 pk_fma(vf2 a, vf2 b, vf2 c) {
    return __builtin_elementwise_fma(a, b, c);
}

// ---------------------------------------------------------------------------
// Repack conv2 weights to vf2 pairs (round-5 proven layout).
// ---------------------------------------------------------------------------
__global__ void repack_kernel(const float* __restrict__ w2, float* __restrict__ wpk)
{
    int i = blockIdx.x * 256 + threadIdx.x;
    if (i < 4608) {
        int h = i & 1, p = i >> 1;
        int k = p % 9, r = p / 9;
        int q = r & 15, ic = r >> 4;
        wpk[i] = w2[(2 * q + h) * 144 + ic * 9 + k];
    }
}

// ---------------------------------------------------------------------------
// conv1+conv2 (round-5 proven compute). Staging trimmed: border-only zeroing
// (interior overwritten anyway; c1pad cols 10-11 never read) + single barrier.
// FIX vs round 11: inpad border loop is strided (288 > blockDim=256).
// ---------------------------------------------------------------------------
__global__ __launch_bounds__(256) void conv_kernel(
    const float* __restrict__ csi,
    float* __restrict__ c2,
    const float* __restrict__ w1, const float* __restrict__ b1,
    const float* __restrict__ wpk, const float* __restrict__ b2)
{
    __shared__ float sw1[288];
    __shared__ float sb1[16];
    __shared__ float sb2[32];
    __shared__ float inpad[4][2][10][10];
    __shared__ float c1pad[7712];
    const int tid = threadIdx.x;

    for (int i = tid; i < 288; i += 256) sw1[i] = w1[i];
    if (tid < 16) sb1[tid] = b1[tid];
    if (tid < 32) sb2[tid] = b2[tid];
    // inpad border zeros (8 (si,c) planes x 36 border cells of 10x10)
    for (int i = tid; i < 288; i += 256) {
        int sc = i / 36, r = i % 36;
        int row, col;
        if (r < 10)      { row = 0; col = r; }
        else if (r < 20) { row = 9; col = r - 10; }
        else if (r < 28) { row = r - 19; col = 0; }
        else             { row = r - 27; col = 9; }
        inpad[sc >> 1][sc & 1][row][col] = 0.f;
    }
    // c1pad border zeros (64 (si,oc) planes x 36 cells; cols 10,11 never read)
    for (int i = tid; i < 2304; i += 256) {
        int so = i / 36, r = i % 36;
        int row, col;
        if (r < 10)      { row = 0; col = r; }
        else if (r < 20) { row = 9; col = r - 10; }
        else if (r < 28) { row = r - 19; col = 0; }
        else             { row = r - 27; col = 9; }
        c1pad[(so >> 4) * 1928 + (so & 15) * 120 + row * 12 + col] = 0.f;
    }
    const long s0 = (long)blockIdx.x * 4;
    for (int i = tid; i < 512; i += 256) {
        int si = i >> 7, r = i & 127;
        int f = r >> 4, t = (r >> 1) & 7, c = r & 1;
        inpad[si][c][f + 1][t + 1] = csi[s0 * 128 + i];
    }
    __syncthreads();

    // conv1: 4096 outputs, 16 per thread
    for (int j = 0; j < 16; ++j) {
        int idx = tid + j * 256;
        int t = idx & 7, f = (idx >> 3) & 7, oc = (idx >> 6) & 15, si = idx >> 10;
        float acc = sb1[oc];
        #pragma unroll
        for (int ic = 0; ic < 2; ++ic)
            #pragma unroll
            for (int df = 0; df < 3; ++df)
                #pragma unroll
                for (int dt = 0; dt < 3; ++dt)
                    acc += inpad[si][ic][f + df][t + dt] * sw1[((oc * 2 + ic) * 3 + df) * 3 + dt];
        c1pad[si * 1928 + oc * 120 + (f + 1) * 12 + (t + 1)] = fmaxf(acc, 0.f);
    }
    __syncthreads();

    // conv2
    const int wv = __builtin_amdgcn_readfirstlane(tid >> 6);
    const int lane = tid & 63;
    const int pos = lane & 31;
    const int si = pos >> 3, fr = pos & 7;
    const int th = lane >> 5, tb = th * 4;
    const vf2* __restrict__ wv2 = (const vf2*)wpk;

    vf2 accp[4][4];
    #pragma unroll
    for (int op = 0; op < 4; ++op) {
        int q = wv * 4 + op;
        vf2 b = {sb2[2 * q], sb2[2 * q + 1]};
        #pragma unroll
        for (int t = 0; t < 4; ++t) accp[op][t] = b;
    }

    for (int ic = 0; ic < 16; ++ic) {
        float rr[3][6];
        const int base = si * 1928 + ic * 120 + fr * 12 + tb;
        #pragma unroll
        for (int r = 0; r < 3; ++r) {
            float4 a = *(const float4*)&c1pad[base + r * 12];
            float2 b = *(const float2*)&c1pad[base + r * 12 + 4];
            rr[r][0] = a.x; rr[r][1] = a.y; rr[r][2] = a.z; rr[r][3] = a.w;
            rr[r][4] = b.x; rr[r][5] = b.y;
        }
        const vf2* wp = wv2 + (size_t)(ic * 16 + wv * 4) * 9;
        vf2 w[36];
        #pragma unroll
        for (int u = 0; u < 36; ++u) w[u] = wp[u];
        #pragma unroll
        for (int op = 0; op < 4; ++op) {
            #pragma unroll
            for (int df = 0; df < 3; ++df)
                #pragma unroll
                for (int dt = 0; dt < 3; ++dt) {
                    vf2 wq = w[op * 9 + df * 3 + dt];
                    #pragma unroll
                    for (int t = 0; t < 4; ++t) {
                        vf2 sv = {rr[df][t + dt], rr[df][t + dt]};
                        accp[op][t] = pk_fma(sv, wq, accp[op][t]);
                    }
                }
        }
    }
    #pragma unroll
    for (int op = 0; op < 4; ++op) {
        int q = wv * 4 + op;
        float4 lo, hi;
        lo.x = fmaxf(accp[op][0].x, 0.f); lo.y = fmaxf(accp[op][1].x, 0.f);
        lo.z = fmaxf(accp[op][2].x, 0.f); lo.w = fmaxf(accp[op][3].x, 0.f);
        hi.x = fmaxf(accp[op][0].y, 0.f); hi.y = fmaxf(accp[op][1].y, 0.f);
        hi.z = fmaxf(accp[op][2].y, 0.f); hi.w = fmaxf(accp[op][3].y, 0.f);
        *(float4*)&c2[(s0 + si) * 2048 + (long)(2 * q) * 64 + fr * 8 + tb] = lo;
        *(float4*)&c2[(s0 + si) * 2048 + (long)(2 * q + 1) * 64 + fr * 8 + tb] = hi;
    }
}

// ---------------------------------------------------------------------------
// fc16 (round-9 proven form): M-tile 16, 4-way K split, As m-major stride-132.
// ---------------------------------------------------------------------------
__global__ __launch_bounds__(256) void fc16_kernel(
    const float* __restrict__ A, const float* __restrict__ W,
    const float* __restrict__ bias, float* __restrict__ out, int K)
{
    __shared__ __align__(16) float smem[16 * ASTR2 + KC * 64];
    float* As = smem;
    float* Ws = smem + 16 * ASTR2;
    const int tid = threadIdx.x;
    const long m0g = (long)blockIdx.x * 16;
    const int ks = tid >> 6;
    const int lane = tid & 63;
    const int m0 = (lane >> 4) * 4;
    const int o0 = (lane & 15) * 4;

    vf2 accp[4][2];
    #pragma unroll
    for (int i = 0; i < 4; ++i) { accp[i][0] = (vf2){0.f, 0.f}; accp[i][1] = (vf2){0.f, 0.f}; }

    for (int kc = 0; kc < K; kc += KC) {
        __syncthreads();
        #pragma unroll
        for (int i = 0; i < 2; ++i) {
            int idx = tid + i * 256;
            int m = idx >> 5, kq = idx & 31;
            float4 v = *(const float4*)&A[(m0g + m) * K + kc + kq * 4];
            *(float4*)&As[m * ASTR2 + kq * 4] = v;
        }
        #pragma unroll
        for (int i = 0; i < 8; ++i) {
            int idx = tid + i * 256;
            int k = idx >> 4, oq = idx & 15;
            *(float4*)&Ws[k * 64 + oq * 4] = *(const float4*)&W[(long)(kc + k) * 64 + oq * 4];
        }
        __syncthreads();
        const int kb = ks * 32;
        #pragma unroll 4
        for (int kk4 = 0; kk4 < 8; ++kk4) {
            const int k0 = kb + kk4 * 4;
            float4 a[4], w[4];
            #pragma unroll
            for (int i = 0; i < 4; ++i) a[i] = *(const float4*)&As[(m0 + i) * ASTR2 + k0];
            #pragma unroll
            for (int j = 0; j < 4; ++j) w[j] = *(const float4*)&Ws[(k0 + j) * 64 + o0];
            #pragma unroll
            for (int j = 0; j < 4; ++j) {
                vf2 w01 = {w[j].x, w[j].y}, w23 = {w[j].z, w[j].w};
                float av[4] = {j == 0 ? a[0].x : (j == 1 ? a[0].y : (j == 2 ? a[0].z : a[0].w)),
                               j == 0 ? a[1].x : (j == 1 ? a[1].y : (j == 2 ? a[1].z : a[1].w)),
                               j == 0 ? a[2].x : (j == 1 ? a[2].y : (j == 2 ? a[2].z : a[2].w)),
                               j == 0 ? a[3].x : (j == 1 ? a[3].y : (j == 2 ? a[3].z : a[3].w))};
                #pragma unroll
                for (int i = 0; i < 4; ++i) {
                    vf2 a2 = {av[i], av[i]};
                    accp[i][0] = pk_fma(a2, w01, accp[i][0]);
                    accp[i][1] = pk_fma(a2, w23, accp[i][1]);
                }
            }
        }
    }
    __syncthreads();
    float* red = smem;
    #pragma unroll
    for (int i = 0; i < 4; ++i) {
        red[(ks * 16 + m0 + i) * 64 + o0 + 0] = accp[i][0].x;
        red[(ks * 16 + m0 + i) * 64 + o0 + 1] = accp[i][0].y;
        red[(ks * 16 + m0 + i) * 64 + o0 + 2] = accp[i][1].x;
        red[(ks * 16 + m0 + i) * 64 + o0 + 3] = accp[i][1].y;
    }
    __syncthreads();
    {
        int m = tid >> 4, oq = tid & 15;
        float4 r0 = *(float4*)&red[(0 * 16 + m) * 64 + oq * 4];
        float4 r1 = *(float4*)&red[(1 * 16 + m) * 64 + oq * 4];
        float4 r2 = *(float4*)&red[(2 * 16 + m) * 64 + oq * 4];
        float4 r3 = *(float4*)&red[(3 * 16 + m) * 64 + oq * 4];
        const float4 b4 = *(const float4*)&bias[oq * 4];
        float4 o4;
        o4.x = fmaxf(r0.x + r1.x + r2.x + r3.x + b4.x, 0.f);
        o4.y = fmaxf(r0.y + r1.y + r2.y + r3.y + b4.y, 0.f);
        o4.z = fmaxf(r0.z + r1.z + r2.z + r3.z + b4.z, 0.f);
        o4.w = fmaxf(r0.w + r1.w + r2.w + r3.w + b4.w, 0.f);
        *(float4*)&out[(m0g + m) * 64 + oq * 4] = o4;
    }
}

// ---------------------------------------------------------------------------
// Device merge + fused xnorm; block 0 additionally computes the AP encoder.
// ---------------------------------------------------------------------------
__global__ __launch_bounds__(256) void merge_kernel(
    const float* __restrict__ dpos, const int* __restrict__ pkts,
    const float* __restrict__ csif,
    const float* __restrict__ Wp, const float* __restrict__ bp,
    const float* __restrict__ Wm, const float* __restrict__ bm,
    const int* __restrict__ degout,
    float* __restrict__ hdev, float* __restrict__ xn,
    const float* __restrict__ appos, const float* __restrict__ Wap,
    const float* __restrict__ bap, const int* __restrict__ degapo,
    float* __restrict__ hap, float* __restrict__ xnap)
{
    __shared__ float sWm[80][64];
    __shared__ float spos[4][16];
    __shared__ float scf[4][64];
    const int tid = threadIdx.x;
    for (int i = tid; i < 5120; i += 256) sWm[i >> 6][i & 63] = Wm[i];
    const int n0 = blockIdx.x * 4;
    (&scf[0][0])[tid] = csif[(long)n0 * 64 + tid];
    if (tid < 64) {
        int dl = tid >> 4, o = tid & 15;
        int d = n0 + dl;
        float px = dpos[d * 2], py = dpos[d * 2 + 1], pk = (float)pkts[d];
        float v = bp[o] + px * Wp[o] + py * Wp[16 + o] + pk * Wp[32 + o];
        spos[dl][o] = fmaxf(v, 0.f);
    }
    __syncthreads();
    const int o = tid & 63, dl = tid >> 6;
    float h = bm[o];
    #pragma unroll
    for (int j = 0; j < 16; ++j) h += spos[dl][j] * sWm[j][o];
    #pragma unroll 8
    for (int j = 0; j < 64; ++j) h += scf[dl][j] * sWm[16 + j][o];
    h = fmaxf(h, 0.f);
    const long idx = (long)(n0 + dl) * 64 + o;
    hdev[idx] = h;
    xn[idx] = h * rsqrtf(fmaxf((float)degout[n0 + dl], 1.f));
    if (blockIdx.x == 0) {
        int a = tid >> 6, oo = tid & 63;
        float v = fmaxf(bap[oo] + appos[a * 2] * Wap[oo] + appos[a * 2 + 1] * Wap[64 + oo], 0.f);
        hap[tid] = v;
        xnap[tid] = v * rsqrtf(fmaxf((float)degapo[a], 1.f));
    }
}

// ---------------------------------------------------------------------------
__global__ __launch_bounds__(256) void degrees_kernel(
    const int* __restrict__ dd_src, const int* __restrict__ dd_dst,
    const int* __restrict__ da_src, const int* __restrict__ da_dst,
    const int* __restrict__ ad_src, const int* __restrict__ ad_dst,
    int* deg_dd_out, int* deg_dd_in, int* deg_da_out, int* deg_ad_in, int* deg_small)
{
    __shared__ int s4[16];
    const int tid = threadIdx.x;
    if (tid < 16) s4[tid] = 0;
    __syncthreads();
    const int gid = blockIdx.x * 256 + tid;
    atomicAdd(&deg_dd_out[dd_src[gid]], 1);
    atomicAdd(&deg_dd_in[dd_dst[gid]], 1);
    if (gid < EDA) {
        atomicAdd(&deg_da_out[da_src[gid]], 1);
        atomicAdd(&s4[da_dst[gid]], 1);
        atomicAdd(&s4[8 + ad_src[gid]], 1);
        atomicAdd(&deg_ad_in[ad_dst[gid]], 1);
    }
    __syncthreads();
    if (tid < 16 && s4[tid] != 0) atomicAdd(&deg_small[tid], s4[tid]);
}

__global__ __launch_bounds__(1024) void scan_kernel(
    const int* __restrict__ degA, int* rsA, int* curA,
    const int* __restrict__ degB, int* rsB, int* curB)
{
    const int* deg = blockIdx.x ? degB : degA;
    int* rs = blockIdx.x ? rsB : rsA;
    int* cur = blockIdx.x ? curB : curA;
    __shared__ int sd[1024];
    const int tid = threadIdx.x;
    const int base = tid * 8;
    int v[8]; int s = 0;
    #pragma unroll
    for (int j = 0; j < 8; ++j) { v[j] = deg[base + j]; s += v[j]; }
    sd[tid] = s;
    __syncthreads();
    for (int off = 1; off < 1024; off <<= 1) {
        int t = (tid >= off) ? sd[tid - off] : 0;
        __syncthreads();
        sd[tid] += t;
        __syncthreads();
    }
    int ex = sd[tid] - s;
    #pragma unroll
    for (int j = 0; j < 8; ++j) { rs[base + j] = ex; cur[base + j] = ex; ex += v[j]; }
}

__global__ __launch_bounds__(256) void reorder_kernel(
    const int* __restrict__ src, const int* __restrict__ dst,
    int* __restrict__ cursor, int* __restrict__ ssrc, int nE)
{
    int e = blockIdx.x * 256 + threadIdx.x;
    if (e < nE) {
        int pos = atomicAdd(&cursor[dst[e]], 1);
        ssrc[pos] = src[e];
    }
}

// ---------------------------------------------------------------------------
// Fused gather launch: blocks [0,2048) dd-gather, [2048,4096) ad-gather,
// [4096,4352) da LDS-reduce (layer 1 only).
// ---------------------------------------------------------------------------
__global__ __launch_bounds__(256) void gatherx_kernel(
    const int* __restrict__ rsdd, const int* __restrict__ degddi,
    const int* __restrict__ ssdd, const float* __restrict__ xn, float* __restrict__ aggdd,
    const int* __restrict__ rsad, const int* __restrict__ degadi,
    const int* __restrict__ ssad, const float* __restrict__ xnap, float* __restrict__ aggad,
    const int* __restrict__ da_src, const int* __restrict__ da_dst,
    const float* __restrict__ hdev, const int* __restrict__ degdao,
    float* __restrict__ aggda)
{
    __shared__ float sacc[4][64];
    const int b = blockIdx.x;
    const int tid = threadIdx.x;
    if (b < 4096) {
        const int w = __builtin_amdgcn_readfirstlane(tid >> 6);
        const int f = tid & 63;
        const bool isdd = b < 2048;
        const int d = (isdd ? b : b - 2048) * 4 + w;
        const int* rs = isdd ? rsdd : rsad;
        const int* dg = isdd ? degddi : degadi;
        const int* ss = isdd ? ssdd : ssad;
        const float* x = isdd ? xn : xnap;
        float* agg = isdd ? aggdd : aggad;
        const int start = rs[d], len = dg[d];
        float acc = 0.f;
        int j = 0;
        for (; j + 4 <= len; j += 4) {
            int s0 = ss[start + j], s1 = ss[start + j + 1];
            int s2 = ss[start + j + 2], s3 = ss[start + j + 3];
            float v0 = x[(long)s0 * 64 + f], v1 = x[(long)s1 * 64 + f];
            float v2 = x[(long)s2 * 64 + f], v3 = x[(long)s3 * 64 + f];
            acc += (v0 + v1) + (v2 + v3);
        }
        for (; j < len; ++j) acc += x[(long)ss[start + j] * 64 + f];
        agg[(long)d * 64 + f] = acc * rsqrtf(fmaxf((float)len, 1.f));
    } else {
        (&sacc[0][0])[tid] = 0.f;
        __syncthreads();
        const int f = tid & 63;
        const int base = (b - 4096) * 128;
        for (int e = base + (tid >> 6); e < base + 128; e += 4) {
            int s = da_src[e], d = da_dst[e];
            float sc = rsqrtf(fmaxf((float)degdao[s], 1.f));
            atomicAdd(&sacc[d][f], hdev[(long)s * 64 + f] * sc);
        }
        __syncthreads();
        float v = (&sacc[0][0])[tid];
        if (v != 0.f) atomicAdd(&aggda[tid], v);
    }
}

// ---------------------------------------------------------------------------
// Fused combine: blocks [0,2048) hd (two relations); block 2048 (layer 1) ha.
// ---------------------------------------------------------------------------
__global__ __launch_bounds__(256) void combinex_kernel(
    const float* __restrict__ agg1, const float* __restrict__ W1, const float* __restrict__ b1,
    const float* __restrict__ agg2, const float* __restrict__ W2, const float* __restrict__ b2,
    const int* __restrict__ degout, float* __restrict__ out, float* __restrict__ xnout,
    const float* __restrict__ aggda, const int* __restrict__ degdai,
    const float* __restrict__ Wda, const float* __restrict__ bda,
    const int* __restrict__ degapo, float* __restrict__ ha_out, float* __restrict__ ha_xn)
{
    __shared__ float sW1[64][64];
    __shared__ float sW2[64][64];
    __shared__ float sa1[4][64];
    __shared__ float sa2[4][64];
    const int tid = threadIdx.x;
    if (blockIdx.x < 2048) {
        for (int i = tid; i < 4096; i += 256) { sW1[i >> 6][i & 63] = W1[i]; sW2[i >> 6][i & 63] = W2[i]; }
        const int n0 = blockIdx.x * 4;
        (&sa1[0][0])[tid] = agg1[(long)n0 * 64 + tid];
        (&sa2[0][0])[tid] = agg2[(long)n0 * 64 + tid];
        __syncthreads();
        const int o = tid & 63, dl = tid >> 6;
        float acc1 = 0.f, acc2 = 0.f;
        #pragma unroll 8
        for (int k = 0; k < 64; ++k) {
            acc1 += sa1[dl][k] * sW1[k][o];
            acc2 += sa2[dl][k] * sW2[k][o];
        }
        float h = fmaxf(acc1 + acc2 + b1[o] + b2[o], 0.f);
        const long idx = (long)(n0 + dl) * 64 + o;
        out[idx] = h;
        if (xnout) xnout[idx] = h * rsqrtf(fmaxf((float)degout[n0 + dl], 1.f));
    } else {
        const int o = tid & 63, a = tid >> 6;
        float acc = 0.f;
        for (int k = 0; k < 64; ++k) acc += aggda[a * 64 + k] * Wda[k * 64 + o];
        float r = rsqrtf(fmaxf((float)degdai[a], 1.f));
        float h = fmaxf(acc * r + bda[o], 0.f);
        ha_out[tid] = h;
        ha_xn[tid] = h * rsqrtf(fmaxf((float)degapo[a], 1.f));
    }
}

// ---------------------------------------------------------------------------
__global__ __launch_bounds__(256) void head_kernel(
    const float* __restrict__ hd2,
    const float* __restrict__ W1, const float* __restrict__ b1,
    const float* __restrict__ W2, const float* __restrict__ b2,
    float* __restrict__ logits_out)
{
    __shared__ float sW1[64][64];
    __shared__ float sW2[64][32];
    __shared__ float sh[4][64];
    __shared__ float st[4][64];
    const int tid = threadIdx.x;
    for (int i = tid; i < 4096; i += 256) sW1[i >> 6][i & 63] = W1[i];
    for (int i = tid; i < 2048; i += 256) sW2[i >> 5][i & 31] = W2[i];
    const int n0 = blockIdx.x * 4;
    (&sh[0][0])[tid] = hd2[(long)n0 * 64 + tid];
    __syncthreads();
    const int o = tid & 63, dl = tid >> 6;
    float acc = b1[o];
    #pragma unroll 8
    for (int k = 0; k < 64; ++k) acc += sh[dl][k] * sW1[k][o];
    st[dl][o] = fmaxf(acc, 0.f);
    __syncthreads();
    if (tid < 128) {
        int j = tid & 31, d2 = tid >> 5;
        float a2 = b2[j];
        #pragma unroll 8
        for (int k = 0; k < 64; ++k) a2 += st[d2][k] * sW2[k][j];
        logits_out[(long)(n0 + d2) * 32 + j] = a2;
    }
}

// ---------------------------------------------------------------------------
__global__ __launch_bounds__(1024) void softmax_stats_kernel(
    const float* __restrict__ logits,
    float* __restrict__ smax, int* __restrict__ sargm, float* __restrict__ ssum)
{
    __shared__ float smx[1024];
    __shared__ int sid[1024];
    __shared__ float ssm[1024];
    const int j = blockIdx.x;
    const int tid = threadIdx.x;
    float best = -__builtin_inff(); int bid = 0x7fffffff;
    for (int n = tid; n < NDEV; n += 1024) {
        float v = logits[n * 32 + j];
        if (v > best) { best = v; bid = n; }
    }
    smx[tid] = best; sid[tid] = bid;
    __syncthreads();
    for (int s = 512; s > 0; s >>= 1) {
        if (tid < s) {
            float v2 = smx[tid + s]; int i2 = sid[tid + s];
            if (v2 > smx[tid] || (v2 == smx[tid] && i2 < sid[tid])) { smx[tid] = v2; sid[tid] = i2; }
        }
        __syncthreads();
    }
    const float mx = smx[0];
    float part = 0.f;
    for (int n = tid; n < NDEV; n += 1024) part += expf(logits[n * 32 + j] - mx);
    ssm[tid] = part;
    __syncthreads();
    for (int s = 512; s > 0; s >>= 1) {
        if (tid < s) ssm[tid] += ssm[tid + s];
        __syncthreads();
    }
    if (tid == 0) { smax[j] = mx; sargm[j] = sid[0]; ssum[j] = ssm[0]; }
}

__global__ __launch_bounds__(256) void final_kernel(
    const float* __restrict__ logits, const float* __restrict__ smax,
    const int* __restrict__ sargm, const float* __restrict__ ssum,
    float* __restrict__ hard, float* __restrict__ soft)
{
    const int gid = blockIdx.x * 256 + threadIdx.x;
    const int n = gid >> 3, t = gid & 7;
    float s = 0.f; int h = 0;
    #pragma unroll
    for (int a = 0; a < 4; ++a) {
        int j = t * 4 + a;
        s += expf(logits[n * 32 + j] - smax[j]) / ssum[j];
        h |= (sargm[j] == n) ? 1 : 0;
    }
    hard[gid] = (float)h;
    soft[gid] = s;
}

// ---------------------------------------------------------------------------
extern "C" void kernel_launch(void* const* d_in, const int* in_sizes, int n_in,
                              void* d_out, int out_size, void* d_ws, size_t ws_size,
                              hipStream_t stream)
{
    const float* device_pos = (const float*)d_in[0];
    const float* ap_pos     = (const float*)d_in[1];
    const float* csi        = (const float*)d_in[2];
    const int*   node_pk    = (const int*)d_in[3];
    const int* dd_src = (const int*)d_in[4];
    const int* dd_dst = (const int*)d_in[5];
    const int* da_src = (const int*)d_in[6];
    const int* da_dst = (const int*)d_in[7];
    const int* ad_src = (const int*)d_in[8];
    const int* ad_dst = (const int*)d_in[9];
    const float* w1  = (const float*)d_in[10]; const float* b1  = (const float*)d_in[11];
    const float* w2  = (const float*)d_in[12]; const float* b2  = (const float*)d_in[13];
    const float* fcW = (const float*)d_in[14]; const float* fcb = (const float*)d_in[15];
    const float* Wp  = (const float*)d_in[16]; const float* bp  = (const float*)d_in[17];
    const float* Wc  = (const float*)d_in[18]; const float* bc  = (const float*)d_in[19];
    const float* Wm  = (const float*)d_in[20]; const float* bm  = (const float*)d_in[21];
    const float* Wap = (const float*)d_in[22]; const float* bap = (const float*)d_in[23];
    const float* g1ddW = (const float*)d_in[24]; const float* g1ddb = (const float*)d_in[25];
    const float* g1daW = (const float*)d_in[26]; const float* g1dab = (const float*)d_in[27];
    const float* g1adW = (const float*)d_in[28]; const float* g1adb = (const float*)d_in[29];
    const float* g2ddW = (const float*)d_in[30]; const float* g2ddb = (const float*)d_in[31];
    const float* g2adW = (const float*)d_in[34]; const float* g2adb = (const float*)d_in[35];
    const float* a1W = (const float*)d_in[36]; const float* a1b = (const float*)d_in[37];
    const float* a2W = (const float*)d_in[38]; const float* a2b = (const float*)d_in[39];

    float* ws = (float*)d_ws;
    size_t o_c2    = 0;                               // 16,777,216
    size_t o_emb   = o_c2 + (size_t)CHUNK * 2048;
    size_t o_csif  = o_emb + (size_t)NSAMP * 64;
    size_t o_hdev  = o_csif + (size_t)NDEV * 64;
    size_t o_hap   = o_hdev + (size_t)NDEV * 64;      // 256
    size_t o_hd1   = o_hap + 256;
    size_t o_ha1   = o_hd1 + (size_t)NDEV * 64;       // 256
    size_t o_hd2   = o_ha1 + 256;
    size_t o_aggdd = o_hd2 + (size_t)NDEV * 64;
    size_t o_aggad = o_aggdd + (size_t)NDEV * 64;
    size_t o_xn    = o_aggad + (size_t)NDEV * 64;
    size_t o_xnap  = o_xn + (size_t)NDEV * 64;        // 256
    size_t o_wpk   = o_xnap + 256;                    // 4608
    // zero region
    size_t o_zero  = o_wpk + 4608;
    size_t o_degddo = o_zero;
    size_t o_degddi = o_degddo + NDEV;
    size_t o_degdao = o_degddi + NDEV;
    size_t o_degadi = o_degdao + NDEV;
    size_t o_degsm  = o_degadi + NDEV;        // int[16]
    size_t o_aggda  = o_degsm + 16;           // float[256]
    size_t o_zend   = o_aggda + 256;
    // non-zeroed
    size_t o_rsdd  = o_zend;
    size_t o_curdd = o_rsdd + NDEV;
    size_t o_rsad  = o_curdd + NDEV;
    size_t o_curad = o_rsad + NDEV;
    size_t o_ssdd  = o_curad + NDEV;          // int[262144]
    size_t o_ssad  = o_ssdd + EDD;            // int[32768]
    size_t o_smax  = o_ssad + EAD;
    size_t o_ssum  = o_smax + 32;
    size_t o_sargm = o_ssum + 32;

    float* out = (float*)d_out;
    float* out_hard   = out;                 // [8192][8]
    float* out_logits = out + 65536;         // [8192][32]
    float* out_soft   = out + 65536 + 262144;

    hipMemsetAsync((void*)(ws + o_zero), 0, (o_zend - o_zero) * sizeof(float), stream);
    repack_kernel<<<18, 256, 0, stream>>>(w2, ws + o_wpk);

    // graph prep
    degrees_kernel<<<EDD / 256, 256, 0, stream>>>(dd_src, dd_dst, da_src, da_dst, ad_src, ad_dst,
                                                  (int*)(ws + o_degddo), (int*)(ws + o_degddi),
                                                  (int*)(ws + o_degdao), (int*)(ws + o_degadi),
                                                  (int*)(ws + o_degsm));
    scan_kernel<<<2, 1024, 0, stream>>>((int*)(ws + o_degddi), (int*)(ws + o_rsdd), (int*)(ws + o_curdd),
                                        (int*)(ws + o_degadi), (int*)(ws + o_rsad), (int*)(ws + o_curad));
    reorder_kernel<<<EDD / 256, 256, 0, stream>>>(dd_src, dd_dst, (int*)(ws + o_curdd),
                                                  (int*)(ws + o_ssdd), EDD);
    reorder_kernel<<<EAD / 256, 256, 0, stream>>>(ad_src, ad_dst, (int*)(ws + o_curad),
                                                  (int*)(ws + o_ssad), EAD);

    // CSI encoder
    for (int c = 0; c < NSAMP / CHUNK; ++c) {
        const float* csi_c = csi + (size_t)c * CHUNK * 128;
        float* emb_c = ws + o_emb + (size_t)c * CHUNK * 64;
        conv_kernel<<<CHUNK / 4, 256, 0, stream>>>(csi_c, ws + o_c2, w1, b1, ws + o_wpk, b2);
        fc16_kernel<<<CHUNK / 16, 256, 0, stream>>>(ws + o_c2, fcW, fcb, emb_c, 2048);
    }

    // device encoder (merge block 0 also does the AP encoder)
    fc16_kernel<<<NDEV / 16, 256, 0, stream>>>(ws + o_emb, Wc, bc, ws + o_csif, 256);
    merge_kernel<<<NDEV / 4, 256, 0, stream>>>(device_pos, node_pk, ws + o_csif,
                                               Wp, bp, Wm, bm, (int*)(ws + o_degddo),
                                               ws + o_hdev, ws + o_xn,
                                               ap_pos, Wap, bap, (int*)(ws + o_degsm) + 8,
                                               ws + o_hap, ws + o_xnap);

    // layer 1 (fused gathers + da; fused combine + ha)
    gatherx_kernel<<<4352, 256, 0, stream>>>((int*)(ws + o_rsdd), (int*)(ws + o_degddi),
                                             (int*)(ws + o_ssdd), ws + o_xn, ws + o_aggdd,
                                             (int*)(ws + o_rsad), (int*)(ws + o_degadi),
                                             (int*)(ws + o_ssad), ws + o_xnap, ws + o_aggad,
                                             da_src, da_dst, ws + o_hdev,
                                             (int*)(ws + o_degdao), ws + o_aggda);
    combinex_kernel<<<2049, 256, 0, stream>>>(ws + o_aggdd, g1ddW, g1ddb,
                                              ws + o_aggad, g1adW, g1adb,
                                              (int*)(ws + o_degddo), ws + o_hd1, ws + o_xn,
                                              ws + o_aggda, (int*)(ws + o_degsm),
                                              g1daW, g1dab, (int*)(ws + o_degsm) + 8,
                                              ws + o_ha1, ws + o_xnap);

    // layer 2
    gatherx_kernel<<<4096, 256, 0, stream>>>((int*)(ws + o_rsdd), (int*)(ws + o_degddi),
                                             (int*)(ws + o_ssdd), ws + o_xn, ws + o_aggdd,
                                             (int*)(ws + o_rsad), (int*)(ws + o_degadi),
                                             (int*)(ws + o_ssad), ws + o_xnap, ws + o_aggad,
                                             da_src, da_dst, ws + o_hd1,
                                             (int*)(ws + o_degdao), ws + o_aggda);
    combinex_kernel<<<2048, 256, 0, stream>>>(ws + o_aggdd, g2ddW, g2ddb,
                                              ws + o_aggad, g2adW, g2adb,
                                              (int*)(ws + o_degddo), ws + o_hd2, nullptr,
                                              nullptr, nullptr, nullptr, nullptr,
                                              nullptr, nullptr, nullptr);

    head_kernel<<<NDEV / 4, 256, 0, stream>>>(ws + o_hd2, a1W, a1b, a2W, a2b, out_logits);

    softmax_stats_kernel<<<32, 1024, 0, stream>>>(out_logits, ws + o_smax,
                                                  (int*)(ws + o_sargm), ws + o_ssum);
    final_kernel<<<65536 / 256, 256, 0, stream>>>(out_logits, ws + o_smax,
                                                  (int*)(ws + o_sargm), ws + o_ssum,
                                                  out_hard, out_soft);
    (void)in_sizes; (void)n_in; (void)out_size; (void)ws_size;
}

// Round 13
// 675.620 us; speedup vs baseline: 1.1372x; 1.0555x over previous
//
#include <hip/hip_runtime.h>

#define NDEV 8192
#define NAP  4
#define NSAMP 32768
#define EDD 262144
#define EDA 32768
#define EAD 32768
#define CHUNK 8192
#define KC 128
#define ASTR2 132

typedef float vf2 __attribute__((ext_vector_type(2)));
static __device__ __forceinline__ vf2 pk_fma(vf2 a, vf2 b, vf2 c) {
    return __builtin_elementwise_fma(a, b, c);
}

// ---------------------------------------------------------------------------
// Repack conv2 weights to vf2 pairs (proven layout) and conv1 weights to
// oc-pair vf2: w1p[v]={w1[2*o2][r], w1[2*o2+1][r]}, v=r*8+o2, r=ic*9+k (288 fl).
// ---------------------------------------------------------------------------
__global__ void repack_kernel(const float* __restrict__ w2, float* __restrict__ wpk,
                              const float* __restrict__ w1, float* __restrict__ w1p)
{
    int i = blockIdx.x * 256 + threadIdx.x;
    if (i < 4608) {
        int h = i & 1, p = i >> 1;
        int k = p % 9, r = p / 9;
        int q = r & 15, ic = r >> 4;
        wpk[i] = w2[(2 * q + h) * 144 + ic * 9 + k];
    }
    int j = i - 4608;
    if (j >= 0 && j < 288) {
        int h = j & 1, v = j >> 1;       // v = r*8 + o2
        int o2 = v & 7, r = v >> 3;      // r = ic*9+k in [0,18)
        w1p[j] = w1[(2 * o2 + h) * 18 + r];
    }
}

// ---------------------------------------------------------------------------
// conv1+conv2. conv1 restructured: thread = one (si,f,t) position, inputs
// hoisted to regs (18 LDS reads), weights as wave-uniform vf2 broadcasts,
// packed FMAs (144 pk_fma vs 288 fma + 576 LDS). conv2 = round-5 proven.
// ---------------------------------------------------------------------------
__global__ __launch_bounds__(256) void conv_kernel(
    const float* __restrict__ csi,
    float* __restrict__ c2,
    const float* __restrict__ w1p, const float* __restrict__ b1,
    const float* __restrict__ wpk, const float* __restrict__ b2)
{
    __shared__ float sw1p[288];
    __shared__ float sb1[16];
    __shared__ float sb2[32];
    __shared__ float inpad[4][2][10][10];
    __shared__ float c1pad[7712];
    const int tid = threadIdx.x;

    for (int i = tid; i < 288; i += 256) sw1p[i] = w1p[i];
    if (tid < 16) sb1[tid] = b1[tid];
    if (tid < 32) sb2[tid] = b2[tid];
    float* ip = &inpad[0][0][0][0];
    for (int i = tid; i < 800; i += 256) ip[i] = 0.f;
    for (int i = tid; i < 7712; i += 256) c1pad[i] = 0.f;
    __syncthreads();

    const long s0 = (long)blockIdx.x * 4;
    for (int i = tid; i < 512; i += 256) {
        int si = i >> 7, r = i & 127;
        int f = r >> 4, t = (r >> 1) & 7, c = r & 1;
        inpad[si][c][f + 1][t + 1] = csi[s0 * 128 + i];
    }
    __syncthreads();

    // conv1: thread = position (si1, f1, t1); all 16 ocs as 8 vf2 accumulators
    {
        const int si1 = tid >> 6, p1 = tid & 63;
        const int f1 = p1 >> 3, t1 = p1 & 7;
        float inv[18];
        #pragma unroll
        for (int ic = 0; ic < 2; ++ic)
            #pragma unroll
            for (int df = 0; df < 3; ++df)
                #pragma unroll
                for (int dt = 0; dt < 3; ++dt)
                    inv[ic * 9 + df * 3 + dt] = inpad[si1][ic][f1 + df][t1 + dt];
        vf2 a1[8];
        #pragma unroll
        for (int o2 = 0; o2 < 8; ++o2) a1[o2] = (vf2){sb1[2 * o2], sb1[2 * o2 + 1]};
        const vf2* sw1v = (const vf2*)sw1p;
        #pragma unroll
        for (int r = 0; r < 18; ++r) {
            vf2 xv = {inv[r], inv[r]};
            #pragma unroll
            for (int o2 = 0; o2 < 8; ++o2)
                a1[o2] = pk_fma(xv, sw1v[r * 8 + o2], a1[o2]);
        }
        const int cbase = si1 * 1928 + (f1 + 1) * 12 + (t1 + 1);
        #pragma unroll
        for (int o2 = 0; o2 < 8; ++o2) {
            c1pad[cbase + (2 * o2) * 120]     = fmaxf(a1[o2].x, 0.f);
            c1pad[cbase + (2 * o2 + 1) * 120] = fmaxf(a1[o2].y, 0.f);
        }
    }
    __syncthreads();

    // conv2 (unchanged)
    const int wv = __builtin_amdgcn_readfirstlane(tid >> 6);
    const int lane = tid & 63;
    const int pos = lane & 31;
    const int si = pos >> 3, fr = pos & 7;
    const int th = lane >> 5, tb = th * 4;
    const vf2* __restrict__ wv2 = (const vf2*)wpk;

    vf2 accp[4][4];
    #pragma unroll
    for (int op = 0; op < 4; ++op) {
        int q = wv * 4 + op;
        vf2 b = {sb2[2 * q], sb2[2 * q + 1]};
        #pragma unroll
        for (int t = 0; t < 4; ++t) accp[op][t] = b;
    }

    for (int ic = 0; ic < 16; ++ic) {
        float rr[3][6];
        const int base = si * 1928 + ic * 120 + fr * 12 + tb;
        #pragma unroll
        for (int r = 0; r < 3; ++r) {
            float4 a = *(const float4*)&c1pad[base + r * 12];
            float2 b = *(const float2*)&c1pad[base + r * 12 + 4];
            rr[r][0] = a.x; rr[r][1] = a.y; rr[r][2] = a.z; rr[r][3] = a.w;
            rr[r][4] = b.x; rr[r][5] = b.y;
        }
        const vf2* wp = wv2 + (size_t)(ic * 16 + wv * 4) * 9;
        vf2 w[36];
        #pragma unroll
        for (int u = 0; u < 36; ++u) w[u] = wp[u];
        #pragma unroll
        for (int op = 0; op < 4; ++op) {
            #pragma unroll
            for (int df = 0; df < 3; ++df)
                #pragma unroll
                for (int dt = 0; dt < 3; ++dt) {
                    vf2 wq = w[op * 9 + df * 3 + dt];
                    #pragma unroll
                    for (int t = 0; t < 4; ++t) {
                        vf2 sv = {rr[df][t + dt], rr[df][t + dt]};
                        accp[op][t] = pk_fma(sv, wq, accp[op][t]);
                    }
                }
        }
    }
    #pragma unroll
    for (int op = 0; op < 4; ++op) {
        int q = wv * 4 + op;
        float4 lo, hi;
        lo.x = fmaxf(accp[op][0].x, 0.f); lo.y = fmaxf(accp[op][1].x, 0.f);
        lo.z = fmaxf(accp[op][2].x, 0.f); lo.w = fmaxf(accp[op][3].x, 0.f);
        hi.x = fmaxf(accp[op][0].y, 0.f); hi.y = fmaxf(accp[op][1].y, 0.f);
        hi.z = fmaxf(accp[op][2].y, 0.f); hi.w = fmaxf(accp[op][3].y, 0.f);
        *(float4*)&c2[(s0 + si) * 2048 + (long)(2 * q) * 64 + fr * 8 + tb] = lo;
        *(float4*)&c2[(s0 + si) * 2048 + (long)(2 * q + 1) * 64 + fr * 8 + tb] = hi;
    }
}

// ---------------------------------------------------------------------------
// fc16 (round-9 proven form): M-tile 16, 4-way K split, As m-major stride-132.
// ---------------------------------------------------------------------------
__global__ __launch_bounds__(256) void fc16_kernel(
    const float* __restrict__ A, const float* __restrict__ W,
    const float* __restrict__ bias, float* __restrict__ out, int K)
{
    __shared__ __align__(16) float smem[16 * ASTR2 + KC * 64];
    float* As = smem;
    float* Ws = smem + 16 * ASTR2;
    const int tid = threadIdx.x;
    const long m0g = (long)blockIdx.x * 16;
    const int ks = tid >> 6;
    const int lane = tid & 63;
    const int m0 = (lane >> 4) * 4;
    const int o0 = (lane & 15) * 4;

    vf2 accp[4][2];
    #pragma unroll
    for (int i = 0; i < 4; ++i) { accp[i][0] = (vf2){0.f, 0.f}; accp[i][1] = (vf2){0.f, 0.f}; }

    for (int kc = 0; kc < K; kc += KC) {
        __syncthreads();
        #pragma unroll
        for (int i = 0; i < 2; ++i) {
            int idx = tid + i * 256;
            int m = idx >> 5, kq = idx & 31;
            float4 v = *(const float4*)&A[(m0g + m) * K + kc + kq * 4];
            *(float4*)&As[m * ASTR2 + kq * 4] = v;
        }
        #pragma unroll
        for (int i = 0; i < 8; ++i) {
            int idx = tid + i * 256;
            int k = idx >> 4, oq = idx & 15;
            *(float4*)&Ws[k * 64 + oq * 4] = *(const float4*)&W[(long)(kc + k) * 64 + oq * 4];
        }
        __syncthreads();
        const int kb = ks * 32;
        #pragma unroll 4
        for (int kk4 = 0; kk4 < 8; ++kk4) {
            const int k0 = kb + kk4 * 4;
            float4 a[4], w[4];
            #pragma unroll
            for (int i = 0; i < 4; ++i) a[i] = *(const float4*)&As[(m0 + i) * ASTR2 + k0];
            #pragma unroll
            for (int j = 0; j < 4; ++j) w[j] = *(const float4*)&Ws[(k0 + j) * 64 + o0];
            #pragma unroll
            for (int j = 0; j < 4; ++j) {
                vf2 w01 = {w[j].x, w[j].y}, w23 = {w[j].z, w[j].w};
                float av[4] = {j == 0 ? a[0].x : (j == 1 ? a[0].y : (j == 2 ? a[0].z : a[0].w)),
                               j == 0 ? a[1].x : (j == 1 ? a[1].y : (j == 2 ? a[1].z : a[1].w)),
                               j == 0 ? a[2].x : (j == 1 ? a[2].y : (j == 2 ? a[2].z : a[2].w)),
                               j == 0 ? a[3].x : (j == 1 ? a[3].y : (j == 2 ? a[3].z : a[3].w))};
                #pragma unroll
                for (int i = 0; i < 4; ++i) {
                    vf2 a2 = {av[i], av[i]};
                    accp[i][0] = pk_fma(a2, w01, accp[i][0]);
                    accp[i][1] = pk_fma(a2, w23, accp[i][1]);
                }
            }
        }
    }
    __syncthreads();
    float* red = smem;
    #pragma unroll
    for (int i = 0; i < 4; ++i) {
        red[(ks * 16 + m0 + i) * 64 + o0 + 0] = accp[i][0].x;
        red[(ks * 16 + m0 + i) * 64 + o0 + 1] = accp[i][0].y;
        red[(ks * 16 + m0 + i) * 64 + o0 + 2] = accp[i][1].x;
        red[(ks * 16 + m0 + i) * 64 + o0 + 3] = accp[i][1].y;
    }
    __syncthreads();
    {
        int m = tid >> 4, oq = tid & 15;
        float4 r0 = *(float4*)&red[(0 * 16 + m) * 64 + oq * 4];
        float4 r1 = *(float4*)&red[(1 * 16 + m) * 64 + oq * 4];
        float4 r2 = *(float4*)&red[(2 * 16 + m) * 64 + oq * 4];
        float4 r3 = *(float4*)&red[(3 * 16 + m) * 64 + oq * 4];
        const float4 b4 = *(const float4*)&bias[oq * 4];
        float4 o4;
        o4.x = fmaxf(r0.x + r1.x + r2.x + r3.x + b4.x, 0.f);
        o4.y = fmaxf(r0.y + r1.y + r2.y + r3.y + b4.y, 0.f);
        o4.z = fmaxf(r0.z + r1.z + r2.z + r3.z + b4.z, 0.f);
        o4.w = fmaxf(r0.w + r1.w + r2.w + r3.w + b4.w, 0.f);
        *(float4*)&out[(m0g + m) * 64 + oq * 4] = o4;
    }
}

// ---------------------------------------------------------------------------
// Device merge + fused xnorm; block 0 additionally computes the AP encoder.
// ---------------------------------------------------------------------------
__global__ __launch_bounds__(256) void merge_kernel(
    const float* __restrict__ dpos, const int* __restrict__ pkts,
    const float* __restrict__ csif,
    const float* __restrict__ Wp, const float* __restrict__ bp,
    const float* __restrict__ Wm, const float* __restrict__ bm,
    const int* __restrict__ degout,
    float* __restrict__ hdev, float* __restrict__ xn,
    const float* __restrict__ appos, const float* __restrict__ Wap,
    const float* __restrict__ bap, const int* __restrict__ degapo,
    float* __restrict__ hap, float* __restrict__ xnap)
{
    __shared__ float sWm[80][64];
    __shared__ float spos[4][16];
    __shared__ float scf[4][64];
    const int tid = threadIdx.x;
    for (int i = tid; i < 5120; i += 256) sWm[i >> 6][i & 63] = Wm[i];
    const int n0 = blockIdx.x * 4;
    (&scf[0][0])[tid] = csif[(long)n0 * 64 + tid];
    if (tid < 64) {
        int dl = tid >> 4, o = tid & 15;
        int d = n0 + dl;
        float px = dpos[d * 2], py = dpos[d * 2 + 1], pk = (float)pkts[d];
        float v = bp[o] + px * Wp[o] + py * Wp[16 + o] + pk * Wp[32 + o];
        spos[dl][o] = fmaxf(v, 0.f);
    }
    __syncthreads();
    const int o = tid & 63, dl = tid >> 6;
    float h = bm[o];
    #pragma unroll
    for (int j = 0; j < 16; ++j) h += spos[dl][j] * sWm[j][o];
    #pragma unroll 8
    for (int j = 0; j < 64; ++j) h += scf[dl][j] * sWm[16 + j][o];
    h = fmaxf(h, 0.f);
    const long idx = (long)(n0 + dl) * 64 + o;
    hdev[idx] = h;
    xn[idx] = h * rsqrtf(fmaxf((float)degout[n0 + dl], 1.f));
    if (blockIdx.x == 0) {
        int a = tid >> 6, oo = tid & 63;
        float v = fmaxf(bap[oo] + appos[a * 2] * Wap[oo] + appos[a * 2 + 1] * Wap[64 + oo], 0.f);
        hap[tid] = v;
        xnap[tid] = v * rsqrtf(fmaxf((float)degapo[a], 1.f));
    }
}

// ---------------------------------------------------------------------------
__global__ __launch_bounds__(256) void degrees_kernel(
    const int* __restrict__ dd_src, const int* __restrict__ dd_dst,
    const int* __restrict__ da_src, const int* __restrict__ da_dst,
    const int* __restrict__ ad_src, const int* __restrict__ ad_dst,
    int* deg_dd_out, int* deg_dd_in, int* deg_da_out, int* deg_ad_in, int* deg_small)
{
    __shared__ int s4[16];
    const int tid = threadIdx.x;
    if (tid < 16) s4[tid] = 0;
    __syncthreads();
    const int gid = blockIdx.x * 256 + tid;
    atomicAdd(&deg_dd_out[dd_src[gid]], 1);
    atomicAdd(&deg_dd_in[dd_dst[gid]], 1);
    if (gid < EDA) {
        atomicAdd(&deg_da_out[da_src[gid]], 1);
        atomicAdd(&s4[da_dst[gid]], 1);
        atomicAdd(&s4[8 + ad_src[gid]], 1);
        atomicAdd(&deg_ad_in[ad_dst[gid]], 1);
    }
    __syncthreads();
    if (tid < 16 && s4[tid] != 0) atomicAdd(&deg_small[tid], s4[tid]);
}

__global__ __launch_bounds__(1024) void scan_kernel(
    const int* __restrict__ degA, int* rsA, int* curA,
    const int* __restrict__ degB, int* rsB, int* curB)
{
    const int* deg = blockIdx.x ? degB : degA;
    int* rs = blockIdx.x ? rsB : rsA;
    int* cur = blockIdx.x ? curB : curA;
    __shared__ int sd[1024];
    const int tid = threadIdx.x;
    const int base = tid * 8;
    int v[8]; int s = 0;
    #pragma unroll
    for (int j = 0; j < 8; ++j) { v[j] = deg[base + j]; s += v[j]; }
    sd[tid] = s;
    __syncthreads();
    for (int off = 1; off < 1024; off <<= 1) {
        int t = (tid >= off) ? sd[tid - off] : 0;
        __syncthreads();
        sd[tid] += t;
        __syncthreads();
    }
    int ex = sd[tid] - s;
    #pragma unroll
    for (int j = 0; j < 8; ++j) { rs[base + j] = ex; cur[base + j] = ex; ex += v[j]; }
}

__global__ __launch_bounds__(256) void reorder_kernel(
    const int* __restrict__ src, const int* __restrict__ dst,
    int* __restrict__ cursor, int* __restrict__ ssrc, int nE)
{
    int e = blockIdx.x * 256 + threadIdx.x;
    if (e < nE) {
        int pos = atomicAdd(&cursor[dst[e]], 1);
        ssrc[pos] = src[e];
    }
}

// ---------------------------------------------------------------------------
// Fused gather launch: blocks [0,2048) dd-gather, [2048,4096) ad-gather,
// [4096,4352) da LDS-reduce (layer 1 only).
// ---------------------------------------------------------------------------
__global__ __launch_bounds__(256) void gatherx_kernel(
    const int* __restrict__ rsdd, const int* __restrict__ degddi,
    const int* __restrict__ ssdd, const float* __restrict__ xn, float* __restrict__ aggdd,
    const int* __restrict__ rsad, const int* __restrict__ degadi,
    const int* __restrict__ ssad, const float* __restrict__ xnap, float* __restrict__ aggad,
    const int* __restrict__ da_src, const int* __restrict__ da_dst,
    const float* __restrict__ hdev, const int* __restrict__ degdao,
    float* __restrict__ aggda)
{
    __shared__ float sacc[4][64];
    const int b = blockIdx.x;
    const int tid = threadIdx.x;
    if (b < 4096) {
        const int w = __builtin_amdgcn_readfirstlane(tid >> 6);
        const int f = tid & 63;
        const bool isdd = b < 2048;
        const int d = (isdd ? b : b - 2048) * 4 + w;
        const int* rs = isdd ? rsdd : rsad;
        const int* dg = isdd ? degddi : degadi;
        const int* ss = isdd ? ssdd : ssad;
        const float* x = isdd ? xn : xnap;
        float* agg = isdd ? aggdd : aggad;
        const int start = rs[d], len = dg[d];
        float acc = 0.f;
        int j = 0;
        for (; j + 4 <= len; j += 4) {
            int s0 = ss[start + j], s1 = ss[start + j + 1];
            int s2 = ss[start + j + 2], s3 = ss[start + j + 3];
            float v0 = x[(long)s0 * 64 + f], v1 = x[(long)s1 * 64 + f];
            float v2 = x[(long)s2 * 64 + f], v3 = x[(long)s3 * 64 + f];
            acc += (v0 + v1) + (v2 + v3);
        }
        for (; j < len; ++j) acc += x[(long)ss[start + j] * 64 + f];
        agg[(long)d * 64 + f] = acc * rsqrtf(fmaxf((float)len, 1.f));
    } else {
        (&sacc[0][0])[tid] = 0.f;
        __syncthreads();
        const int f = tid & 63;
        const int base = (b - 4096) * 128;
        for (int e = base + (tid >> 6); e < base + 128; e += 4) {
            int s = da_src[e], d = da_dst[e];
            float sc = rsqrtf(fmaxf((float)degdao[s], 1.f));
            atomicAdd(&sacc[d][f], hdev[(long)s * 64 + f] * sc);
        }
        __syncthreads();
        float v = (&sacc[0][0])[tid];
        if (v != 0.f) atomicAdd(&aggda[tid], v);
    }
}

// ---------------------------------------------------------------------------
// Fused combine: blocks [0,2048) hd (two relations); block 2048 (layer 1) ha.
// ---------------------------------------------------------------------------
__global__ __launch_bounds__(256) void combinex_kernel(
    const float* __restrict__ agg1, const float* __restrict__ W1, const float* __restrict__ b1,
    const float* __restrict__ agg2, const float* __restrict__ W2, const float* __restrict__ b2,
    const int* __restrict__ degout, float* __restrict__ out, float* __restrict__ xnout,
    const float* __restrict__ aggda, const int* __restrict__ degdai,
    const float* __restrict__ Wda, const float* __restrict__ bda,
    const int* __restrict__ degapo, float* __restrict__ ha_out, float* __restrict__ ha_xn)
{
    __shared__ float sW1[64][64];
    __shared__ float sW2[64][64];
    __shared__ float sa1[4][64];
    __shared__ float sa2[4][64];
    const int tid = threadIdx.x;
    if (blockIdx.x < 2048) {
        for (int i = tid; i < 4096; i += 256) { sW1[i >> 6][i & 63] = W1[i]; sW2[i >> 6][i & 63] = W2[i]; }
        const int n0 = blockIdx.x * 4;
        (&sa1[0][0])[tid] = agg1[(long)n0 * 64 + tid];
        (&sa2[0][0])[tid] = agg2[(long)n0 * 64 + tid];
        __syncthreads();
        const int o = tid & 63, dl = tid >> 6;
        float acc1 = 0.f, acc2 = 0.f;
        #pragma unroll 8
        for (int k = 0; k < 64; ++k) {
            acc1 += sa1[dl][k] * sW1[k][o];
            acc2 += sa2[dl][k] * sW2[k][o];
        }
        float h = fmaxf(acc1 + acc2 + b1[o] + b2[o], 0.f);
        const long idx = (long)(n0 + dl) * 64 + o;
        out[idx] = h;
        if (xnout) xnout[idx] = h * rsqrtf(fmaxf((float)degout[n0 + dl], 1.f));
    } else {
        const int o = tid & 63, a = tid >> 6;
        float acc = 0.f;
        for (int k = 0; k < 64; ++k) acc += aggda[a * 64 + k] * Wda[k * 64 + o];
        float r = rsqrtf(fmaxf((float)degdai[a], 1.f));
        float h = fmaxf(acc * r + bda[o], 0.f);
        ha_out[tid] = h;
        ha_xn[tid] = h * rsqrtf(fmaxf((float)degapo[a], 1.f));
    }
}

// ---------------------------------------------------------------------------
__global__ __launch_bounds__(256) void head_kernel(
    const float* __restrict__ hd2,
    const float* __restrict__ W1, const float* __restrict__ b1,
    const float* __restrict__ W2, const float* __restrict__ b2,
    float* __restrict__ logits_out)
{
    __shared__ float sW1[64][64];
    __shared__ float sW2[64][32];
    __shared__ float sh[4][64];
    __shared__ float st[4][64];
    const int tid = threadIdx.x;
    for (int i = tid; i < 4096; i += 256) sW1[i >> 6][i & 63] = W1[i];
    for (int i = tid; i < 2048; i += 256) sW2[i >> 5][i & 31] = W2[i];
    const int n0 = blockIdx.x * 4;
    (&sh[0][0])[tid] = hd2[(long)n0 * 64 + tid];
    __syncthreads();
    const int o = tid & 63, dl = tid >> 6;
    float acc = b1[o];
    #pragma unroll 8
    for (int k = 0; k < 64; ++k) acc += sh[dl][k] * sW1[k][o];
    st[dl][o] = fmaxf(acc, 0.f);
    __syncthreads();
    if (tid < 128) {
        int j = tid & 31, d2 = tid >> 5;
        float a2 = b2[j];
        #pragma unroll 8
        for (int k = 0; k < 64; ++k) a2 += st[d2][k] * sW2[k][j];
        logits_out[(long)(n0 + d2) * 32 + j] = a2;
    }
}

// ---------------------------------------------------------------------------
__global__ __launch_bounds__(1024) void softmax_stats_kernel(
    const float* __restrict__ logits,
    float* __restrict__ smax, int* __restrict__ sargm, float* __restrict__ ssum)
{
    __shared__ float smx[1024];
    __shared__ int sid[1024];
    __shared__ float ssm[1024];
    const int j = blockIdx.x;
    const int tid = threadIdx.x;
    float best = -__builtin_inff(); int bid = 0x7fffffff;
    for (int n = tid; n < NDEV; n += 1024) {
        float v = logits[n * 32 + j];
        if (v > best) { best = v; bid = n; }
    }
    smx[tid] = best; sid[tid] = bid;
    __syncthreads();
    for (int s = 512; s > 0; s >>= 1) {
        if (tid < s) {
            float v2 = smx[tid + s]; int i2 = sid[tid + s];
            if (v2 > smx[tid] || (v2 == smx[tid] && i2 < sid[tid])) { smx[tid] = v2; sid[tid] = i2; }
        }
        __syncthreads();
    }
    const float mx = smx[0];
    float part = 0.f;
    for (int n = tid; n < NDEV; n += 1024) part += expf(logits[n * 32 + j] - mx);
    ssm[tid] = part;
    __syncthreads();
    for (int s = 512; s > 0; s >>= 1) {
        if (tid < s) ssm[tid] += ssm[tid + s];
        __syncthreads();
    }
    if (tid == 0) { smax[j] = mx; sargm[j] = sid[0]; ssum[j] = ssm[0]; }
}

__global__ __launch_bounds__(256) void final_kernel(
    const float* __restrict__ logits, const float* __restrict__ smax,
    const int* __restrict__ sargm, const float* __restrict__ ssum,
    float* __restrict__ hard, float* __restrict__ soft)
{
    const int gid = blockIdx.x * 256 + threadIdx.x;
    const int n = gid >> 3, t = gid & 7;
    float s = 0.f; int h = 0;
    #pragma unroll
    for (int a = 0; a < 4; ++a) {
        int j = t * 4 + a;
        s += expf(logits[n * 32 + j] - smax[j]) / ssum[j];
        h |= (sargm[j] == n) ? 1 : 0;
    }
    hard[gid] = (float)h;
    soft[gid] = s;
}

// ---------------------------------------------------------------------------
extern "C" void kernel_launch(void* const* d_in, const int* in_sizes, int n_in,
                              void* d_out, int out_size, void* d_ws, size_t ws_size,
                              hipStream_t stream)
{
    const float* device_pos = (const float*)d_in[0];
    const float* ap_pos     = (const float*)d_in[1];
    const float* csi        = (const float*)d_in[2];
    const int*   node_pk    = (const int*)d_in[3];
    const int* dd_src = (const int*)d_in[4];
    const int* dd_dst = (const int*)d_in[5];
    const int* da_src = (const int*)d_in[6];
    const int* da_dst = (const int*)d_in[7];
    const int* ad_src = (const int*)d_in[8];
    const int* ad_dst = (const int*)d_in[9];
    const float* w1  = (const float*)d_in[10]; const float* b1  = (const float*)d_in[11];
    const float* w2  = (const float*)d_in[12]; const float* b2  = (const float*)d_in[13];
    const float* fcW = (const float*)d_in[14]; const float* fcb = (const float*)d_in[15];
    const float* Wp  = (const float*)d_in[16]; const float* bp  = (const float*)d_in[17];
    const float* Wc  = (const float*)d_in[18]; const float* bc  = (const float*)d_in[19];
    const float* Wm  = (const float*)d_in[20]; const float* bm  = (const float*)d_in[21];
    const float* Wap = (const float*)d_in[22]; const float* bap = (const float*)d_in[23];
    const float* g1ddW = (const float*)d_in[24]; const float* g1ddb = (const float*)d_in[25];
    const float* g1daW = (const float*)d_in[26]; const float* g1dab = (const float*)d_in[27];
    const float* g1adW = (const float*)d_in[28]; const float* g1adb = (const float*)d_in[29];
    const float* g2ddW = (const float*)d_in[30]; const float* g2ddb = (const float*)d_in[31];
    const float* g2adW = (const float*)d_in[34]; const float* g2adb = (const float*)d_in[35];
    const float* a1W = (const float*)d_in[36]; const float* a1b = (const float*)d_in[37];
    const float* a2W = (const float*)d_in[38]; const float* a2b = (const float*)d_in[39];

    float* ws = (float*)d_ws;
    size_t o_c2    = 0;                               // 16,777,216
    size_t o_emb   = o_c2 + (size_t)CHUNK * 2048;
    size_t o_csif  = o_emb + (size_t)NSAMP * 64;
    size_t o_hdev  = o_csif + (size_t)NDEV * 64;
    size_t o_hap   = o_hdev + (size_t)NDEV * 64;      // 256
    size_t o_hd1   = o_hap + 256;
    size_t o_ha1   = o_hd1 + (size_t)NDEV * 64;       // 256
    size_t o_hd2   = o_ha1 + 256;
    size_t o_aggdd = o_hd2 + (size_t)NDEV * 64;
    size_t o_aggad = o_aggdd + (size_t)NDEV * 64;
    size_t o_xn    = o_aggad + (size_t)NDEV * 64;
    size_t o_xnap  = o_xn + (size_t)NDEV * 64;        // 256
    size_t o_wpk   = o_xnap + 256;                    // 4608
    size_t o_w1p   = o_wpk + 4608;                    // 288
    // zero region
    size_t o_zero  = o_w1p + 288;
    size_t o_degddo = o_zero;
    size_t o_degddi = o_degddo + NDEV;
    size_t o_degdao = o_degddi + NDEV;
    size_t o_degadi = o_degdao + NDEV;
    size_t o_degsm  = o_degadi + NDEV;        // int[16]
    size_t o_aggda  = o_degsm + 16;           // float[256]
    size_t o_zend   = o_aggda + 256;
    // non-zeroed
    size_t o_rsdd  = o_zend;
    size_t o_curdd = o_rsdd + NDEV;
    size_t o_rsad  = o_curdd + NDEV;
    size_t o_curad = o_rsad + NDEV;
    size_t o_ssdd  = o_curad + NDEV;          // int[262144]
    size_t o_ssad  = o_ssdd + EDD;            // int[32768]
    size_t o_smax  = o_ssad + EAD;
    size_t o_ssum  = o_smax + 32;
    size_t o_sargm = o_ssum + 32;

    float* out = (float*)d_out;
    float* out_hard   = out;                 // [8192][8]
    float* out_logits = out + 65536;         // [8192][32]
    float* out_soft   = out + 65536 + 262144;

    hipMemsetAsync((void*)(ws + o_zero), 0, (o_zend - o_zero) * sizeof(float), stream);
    repack_kernel<<<20, 256, 0, stream>>>(w2, ws + o_wpk, w1, ws + o_w1p);

    // graph prep
    degrees_kernel<<<EDD / 256, 256, 0, stream>>>(dd_src, dd_dst, da_src, da_dst, ad_src, ad_dst,
                                                  (int*)(ws + o_degddo), (int*)(ws + o_degddi),
                                                  (int*)(ws + o_degdao), (int*)(ws + o_degadi),
                                                  (int*)(ws + o_degsm));
    scan_kernel<<<2, 1024, 0, stream>>>((int*)(ws + o_degddi), (int*)(ws + o_rsdd), (int*)(ws + o_curdd),
                                        (int*)(ws + o_degadi), (int*)(ws + o_rsad), (int*)(ws + o_curad));
    reorder_kernel<<<EDD / 256, 256, 0, stream>>>(dd_src, dd_dst, (int*)(ws + o_curdd),
                                                  (int*)(ws + o_ssdd), EDD);
    reorder_kernel<<<EAD / 256, 256, 0, stream>>>(ad_src, ad_dst, (int*)(ws + o_curad),
                                                  (int*)(ws + o_ssad), EAD);

    // CSI encoder
    for (int c = 0; c < NSAMP / CHUNK; ++c) {
        const float* csi_c = csi + (size_t)c * CHUNK * 128;
        float* emb_c = ws + o_emb + (size_t)c * CHUNK * 64;
        conv_kernel<<<CHUNK / 4, 256, 0, stream>>>(csi_c, ws + o_c2, ws + o_w1p, b1, ws + o_wpk, b2);
        fc16_kernel<<<CHUNK / 16, 256, 0, stream>>>(ws + o_c2, fcW, fcb, emb_c, 2048);
    }

    // device encoder (merge block 0 also does the AP encoder)
    fc16_kernel<<<NDEV / 16, 256, 0, stream>>>(ws + o_emb, Wc, bc, ws + o_csif, 256);
    merge_kernel<<<NDEV / 4, 256, 0, stream>>>(device_pos, node_pk, ws + o_csif,
                                               Wp, bp, Wm, bm, (int*)(ws + o_degddo),
                                               ws + o_hdev, ws + o_xn,
                                               ap_pos, Wap, bap, (int*)(ws + o_degsm) + 8,
                                               ws + o_hap, ws + o_xnap);

    // layer 1 (fused gathers + da; fused combine + ha)
    gatherx_kernel<<<4352, 256, 0, stream>>>((int*)(ws + o_rsdd), (int*)(ws + o_degddi),
                                             (int*)(ws + o_ssdd), ws + o_xn, ws + o_aggdd,
                                             (int*)(ws + o_rsad), (int*)(ws + o_degadi),
                                             (int*)(ws + o_ssad), ws + o_xnap, ws + o_aggad,
                                             da_src, da_dst, ws + o_hdev,
                                             (int*)(ws + o_degdao), ws + o_aggda);
    combinex_kernel<<<2049, 256, 0, stream>>>(ws + o_aggdd, g1ddW, g1ddb,
                                              ws + o_aggad, g1adW, g1adb,
                                              (int*)(ws + o_degddo), ws + o_hd1, ws + o_xn,
                                              ws + o_aggda, (int*)(ws + o_degsm),
                                              g1daW, g1dab, (int*)(ws + o_degsm) + 8,
                                              ws + o_ha1, ws + o_xnap);

    // layer 2
    gatherx_kernel<<<4096, 256, 0, stream>>>((int*)(ws + o_rsdd), (int*)(ws + o_degddi),
                                             (int*)(ws + o_ssdd), ws + o_xn, ws + o_aggdd,
                                             (int*)(ws + o_rsad), (int*)(ws + o_degadi),
                                             (int*)(ws + o_ssad), ws + o_xnap, ws + o_aggad,
                                             da_src, da_dst, ws + o_hd1,
                                             (int*)(ws + o_degdao), ws + o_aggda);
    combinex_kernel<<<2048, 256, 0, stream>>>(ws + o_aggdd, g2ddW, g2ddb,
                                              ws + o_aggad, g2adW, g2adb,
                                              (int*)(ws + o_degddo), ws + o_hd2, nullptr,
                                              nullptr, nullptr, nullptr, nullptr,
                                              nullptr, nullptr, nullptr);

    head_kernel<<<NDEV / 4, 256, 0, stream>>>(ws + o_hd2, a1W, a1b, a2W, a2b, out_logits);

    softmax_stats_kernel<<<32, 1024, 0, stream>>>(out_logits, ws + o_smax,
                                                  (int*)(ws + o_sargm), ws + o_ssum);
    final_kernel<<<65536 / 256, 256, 0, stream>>>(out_logits, ws + o_smax,
                                                  (int*)(ws + o_sargm), ws + o_ssum,
                                                  out_hard, out_soft);
    (void)in_sizes; (void)n_in; (void)out_size; (void)ws_size;
}